// Round 2
// baseline (318.300 us; speedup 1.0000x reference)
//
#include <hip/hip_runtime.h>

using short8 = __attribute__((ext_vector_type(8))) short;
using f32x4  = __attribute__((ext_vector_type(4))) float;

#define BB 2
#define SS 2048
#define DD 1024
#define HH 16
#define KVH 4
#define HDIM 64
#define NQK 1280    // Q(1024) | K(256) columns of split projection

__device__ __forceinline__ unsigned short f2bf(float f) {
    unsigned int u = __float_as_uint(f);
    u += 0x7FFFu + ((u >> 16) & 1u);
    return (unsigned short)(u >> 16);
}
__device__ __forceinline__ float bf2f(unsigned short h) {
    return __uint_as_float((unsigned int)h << 16);
}

// ---------------------------------------------------------------------------
// Prep: rows 0..1279 -> Wqk hi/lo (Q direct, K pooled+key_scale).
// rows 1280..1535 -> pooled RAW V weights (value_scale unused: reference bug).
// rows 1536..2559 -> Wo bf16. grid 2560 x 256.
__global__ void prep_weights(const float* __restrict__ Wq, const float* __restrict__ Wk,
                             const float* __restrict__ Wv, const float* __restrict__ Wo,
                             const float* __restrict__ ksc,
                             unsigned short* __restrict__ Wqk_h, unsigned short* __restrict__ Wqk_l,
                             unsigned short* __restrict__ Wvb, unsigned short* __restrict__ Wob)
{
    int row = blockIdx.x;
    int c = threadIdx.x * 4;
    if (row < NQK) {
        float vals[4];
        if (row < 1024) {
            #pragma unroll
            for (int j = 0; j < 4; ++j) vals[j] = Wq[(size_t)row * DD + c + j];
        } else {
            int kh = row - 1024;                  // 0..255
            int kvi = kh >> 6, hd = kh & 63;
            #pragma unroll
            for (int j = 0; j < 4; ++j) {
                float s = 0.f;
                #pragma unroll
                for (int g = 0; g < 4; ++g)
                    s += Wk[(size_t)((kvi * 4 + g) * 64 + hd) * DD + c + j] * ksc[kvi * 4 + g];
                vals[j] = s;
            }
        }
        #pragma unroll
        for (int j = 0; j < 4; ++j) {
            unsigned short hi = f2bf(vals[j]);
            Wqk_h[(size_t)row * DD + c + j] = hi;
            Wqk_l[(size_t)row * DD + c + j] = f2bf(vals[j] - bf2f(hi));
        }
    } else if (row < 1536) {
        int vh = row - 1280;
        int kvi = vh >> 6, hd = vh & 63;
        #pragma unroll
        for (int j = 0; j < 4; ++j) {
            float s = 0.f;
            #pragma unroll
            for (int g = 0; g < 4; ++g)
                s += Wv[(size_t)((kvi * 4 + g) * 64 + hd) * DD + c + j];
            Wvb[(size_t)vh * DD + c + j] = f2bf(s);
        }
    } else {
        int r = row - 1536;
        #pragma unroll
        for (int j = 0; j < 4; ++j)
            Wob[(size_t)r * DD + c + j] = f2bf(Wo[(size_t)r * DD + c + j]);
    }
}

// T5 bucket via integer thresholds (matches numpy fp32 logf semantics at all
// integer rel positions; verified boundary cases 12/16/23/32/46/64/91).
__device__ __forceinline__ int rel_large(int rel) { // rel >= 8
    int n;
    if (rel < 12) n = 0; else if (rel < 16) n = 1; else if (rel < 23) n = 2;
    else if (rel < 32) n = 3; else if (rel < 46) n = 4; else if (rel < 64) n = 5;
    else if (rel < 91) n = 6; else if (rel < 128) n = 7; else n = 8;
    int large = 8 + n;
    return large > 15 ? 15 : large;
}

__global__ void build_bias(const float* __restrict__ bias_emb, float* __restrict__ tab)
{
    int idx = blockIdx.x * 256 + threadIdx.x;
    if (idx >= HH * 4095) return;
    int h = idx / 4095;
    int dpos = idx % 4095;
    int d = dpos - 2047;
    int rel = d < 0 ? -d : d;
    int bucket = (rel < 8) ? rel : rel_large(rel);
    if (d > 0) bucket += 16;
    tab[(size_t)h * 4095 + dpos] = bias_emb[bucket * HH + h];
}

// ---------------------------------------------------------------------------
// C[M,N] = A[M,K] @ B[N,K]^T. 128x128 tile, BK=32, 4 waves (2x2), 4x4 frags.
// MODE 0: A bf16,  B bf16        -> C fp32    (output projection)
// MODE 1: A fp32 (->bf16), B bf16 -> C bf16   (V projection)
// MODE 2: A fp32 (->hi/lo), B hi/lo -> C hi/lo (QK projection, 3-term split)
template<int MODE>
__global__ __launch_bounds__(256) void gemm_bt(const void* __restrict__ Ap,
                                               const unsigned short* __restrict__ Bh,
                                               const unsigned short* __restrict__ Bl,
                                               void* __restrict__ Chv, void* __restrict__ Clv,
                                               int M, int N, int K)
{
    __shared__ __align__(16) unsigned short Ash[128 * 40];
    __shared__ __align__(16) unsigned short Bsh[128 * 40];
    __shared__ __align__(16) unsigned short Asl[MODE == 2 ? 128 * 40 : 1];
    __shared__ __align__(16) unsigned short Bsl[MODE == 2 ? 128 * 40 : 1];

    int m0 = blockIdx.y * 128, n0 = blockIdx.x * 128;
    int t = threadIdx.x;
    int wv = t >> 6, lane = t & 63;
    int wm = wv >> 1, wn = wv & 1;
    int lr = lane & 15, lg = lane >> 4;
    f32x4 acc[4][4] = {};

    for (int k0 = 0; k0 < K; k0 += 32) {
        __syncthreads();
        #pragma unroll
        for (int it = 0; it < 2; ++it) {
            int idx = t + it * 256;
            int row = idx >> 2;
            int c = (idx & 3) << 3;
            *(uint4*)(&Bsh[row * 40 + c]) = *(const uint4*)(Bh + (size_t)(n0 + row) * K + k0 + c);
            if constexpr (MODE == 2)
                *(uint4*)(&Bsl[row * 40 + c]) = *(const uint4*)(Bl + (size_t)(n0 + row) * K + k0 + c);
            if constexpr (MODE == 0) {
                *(uint4*)(&Ash[row * 40 + c]) =
                    *(const uint4*)((const unsigned short*)Ap + (size_t)(m0 + row) * K + k0 + c);
            } else {
                const float* Af = (const float*)Ap;
                float4 x0 = *(const float4*)(Af + (size_t)(m0 + row) * K + k0 + c);
                float4 x1 = *(const float4*)(Af + (size_t)(m0 + row) * K + k0 + c + 4);
                float xs[8] = {x0.x, x0.y, x0.z, x0.w, x1.x, x1.y, x1.z, x1.w};
                unsigned short hi[8];
                #pragma unroll
                for (int j = 0; j < 8; ++j) hi[j] = f2bf(xs[j]);
                #pragma unroll
                for (int j = 0; j < 8; ++j) Ash[row * 40 + c + j] = hi[j];
                if constexpr (MODE == 2) {
                    #pragma unroll
                    for (int j = 0; j < 8; ++j)
                        Asl[row * 40 + c + j] = f2bf(xs[j] - bf2f(hi[j]));
                }
            }
        }
        __syncthreads();
        short8 afh[4], bfh[4];
        #pragma unroll
        for (int mi = 0; mi < 4; ++mi)
            afh[mi] = *(const short8*)(&Ash[(wm * 64 + mi * 16 + lr) * 40 + lg * 8]);
        #pragma unroll
        for (int ni = 0; ni < 4; ++ni)
            bfh[ni] = *(const short8*)(&Bsh[(wn * 64 + ni * 16 + lr) * 40 + lg * 8]);
        if constexpr (MODE == 2) {
            short8 afl[4], bfl[4];
            #pragma unroll
            for (int mi = 0; mi < 4; ++mi)
                afl[mi] = *(const short8*)(&Asl[(wm * 64 + mi * 16 + lr) * 40 + lg * 8]);
            #pragma unroll
            for (int ni = 0; ni < 4; ++ni)
                bfl[ni] = *(const short8*)(&Bsl[(wn * 64 + ni * 16 + lr) * 40 + lg * 8]);
            #pragma unroll
            for (int mi = 0; mi < 4; ++mi)
                #pragma unroll
                for (int ni = 0; ni < 4; ++ni) {
                    acc[mi][ni] = __builtin_amdgcn_mfma_f32_16x16x32_bf16(afh[mi], bfh[ni], acc[mi][ni], 0, 0, 0);
                    acc[mi][ni] = __builtin_amdgcn_mfma_f32_16x16x32_bf16(afh[mi], bfl[ni], acc[mi][ni], 0, 0, 0);
                    acc[mi][ni] = __builtin_amdgcn_mfma_f32_16x16x32_bf16(afl[mi], bfh[ni], acc[mi][ni], 0, 0, 0);
                }
        } else {
            #pragma unroll
            for (int mi = 0; mi < 4; ++mi)
                #pragma unroll
                for (int ni = 0; ni < 4; ++ni)
                    acc[mi][ni] = __builtin_amdgcn_mfma_f32_16x16x32_bf16(afh[mi], bfh[ni], acc[mi][ni], 0, 0, 0);
        }
    }

    #pragma unroll
    for (int mi = 0; mi < 4; ++mi) {
        #pragma unroll
        for (int ni = 0; ni < 4; ++ni) {
            #pragma unroll
            for (int r = 0; r < 4; ++r) {
                int row = m0 + wm * 64 + mi * 16 + 4 * lg + r;
                int col = n0 + wn * 64 + ni * 16 + lr;
                float v = acc[mi][ni][r];
                if constexpr (MODE == 0) {
                    ((float*)Chv)[(size_t)row * N + col] = v;
                } else if constexpr (MODE == 1) {
                    ((unsigned short*)Chv)[(size_t)row * N + col] = f2bf(v);
                } else {
                    unsigned short hi = f2bf(v);
                    ((unsigned short*)Chv)[(size_t)row * N + col] = hi;
                    ((unsigned short*)Clv)[(size_t)row * N + col] = f2bf(v - bf2f(hi));
                }
            }
        }
    }
}

// ---------------------------------------------------------------------------
// Flash attention with split-precision QK^T. One block = 64 q-rows of one
// (b,h). K staged hi+lo [64][64] (stride 72), V transposed Vst[d][key].
__global__ __launch_bounds__(256) void attn(const unsigned short* __restrict__ Yh,
                                            const unsigned short* __restrict__ Yl,
                                            const unsigned short* __restrict__ Vb,
                                            const float* __restrict__ tab,
                                            unsigned short* __restrict__ O)
{
    int blk = blockIdx.x;
    int qb = blk & 31, h = (blk >> 5) & 15, b = blk >> 9;
    int kv = h >> 2;
    int q0 = qb * 64;
    int t = threadIdx.x, w = t >> 6, lane = t & 63, lr = lane & 15, lg = lane >> 4;

    __shared__ __align__(16) unsigned short Ksh[64 * 72];
    __shared__ __align__(16) unsigned short Ksl[64 * 72];
    __shared__ __align__(16) unsigned short Vst[64 * 72];
    __shared__ __align__(16) unsigned short Ps[4][16 * 72];
    __shared__ float bias_s[128];

    const size_t yoff = (size_t)(b * SS + q0 + w * 16 + lr) * NQK + h * 64;
    short8 aq0h = *(const short8*)(Yh + yoff + lg * 8);
    short8 aq1h = *(const short8*)(Yh + yoff + 32 + lg * 8);
    short8 aq0l = *(const short8*)(Yl + yoff + lg * 8);
    short8 aq1l = *(const short8*)(Yl + yoff + 32 + lg * 8);

    f32x4 acc_o[4] = {};
    float m[4], l[4];
    #pragma unroll
    for (int r = 0; r < 4; ++r) { m[r] = -1e30f; l[r] = 0.f; }

    for (int key0 = 0; key0 < SS; key0 += 64) {
        __syncthreads();
        #pragma unroll
        for (int it = 0; it < 2; ++it) {
            int idx = t + it * 256;
            int row = idx >> 3, c = (idx & 7) << 3;
            size_t srck = (size_t)(b * SS + key0 + row) * NQK + 1024 + kv * 64 + c;
            *(uint4*)(&Ksh[row * 72 + c]) = *(const uint4*)(Yh + srck);
            *(uint4*)(&Ksl[row * 72 + c]) = *(const uint4*)(Yl + srck);
            uint4 vvl = *(const uint4*)(Vb + (size_t)(b * SS + key0 + row) * 256 + kv * 64 + c);
            const unsigned short* vp = (const unsigned short*)&vvl;
            #pragma unroll
            for (int q = 0; q < 8; ++q) Vst[(c + q) * 72 + row] = vp[q];
        }
        if (t < 128) {
            int ti = key0 - q0 + t - 63 + 2047;
            ti = ti < 0 ? 0 : (ti > 4094 ? 4094 : ti);
            bias_s[t] = tab[(size_t)h * 4095 + ti];
        }
        __syncthreads();

        // QK^T split: scores D[i=4*lg+r][j=dt*16+lr]
        f32x4 z = {0.f, 0.f, 0.f, 0.f};
        f32x4 sc[4];
        #pragma unroll
        for (int dt = 0; dt < 4; ++dt) {
            short8 bk0h = *(const short8*)(&Ksh[(dt * 16 + lr) * 72 + lg * 8]);
            short8 bk1h = *(const short8*)(&Ksh[(dt * 16 + lr) * 72 + 32 + lg * 8]);
            short8 bk0l = *(const short8*)(&Ksl[(dt * 16 + lr) * 72 + lg * 8]);
            short8 bk1l = *(const short8*)(&Ksl[(dt * 16 + lr) * 72 + 32 + lg * 8]);
            f32x4 s = __builtin_amdgcn_mfma_f32_16x16x32_bf16(aq0h, bk0h, z, 0, 0, 0);
            s = __builtin_amdgcn_mfma_f32_16x16x32_bf16(aq1h, bk1h, s, 0, 0, 0);
            s = __builtin_amdgcn_mfma_f32_16x16x32_bf16(aq0h, bk0l, s, 0, 0, 0);
            s = __builtin_amdgcn_mfma_f32_16x16x32_bf16(aq1h, bk1l, s, 0, 0, 0);
            s = __builtin_amdgcn_mfma_f32_16x16x32_bf16(aq0l, bk0h, s, 0, 0, 0);
            s = __builtin_amdgcn_mfma_f32_16x16x32_bf16(aq1l, bk1h, s, 0, 0, 0);
            sc[dt] = s;
        }
        #pragma unroll
        for (int dt = 0; dt < 4; ++dt)
            #pragma unroll
            for (int r = 0; r < 4; ++r)
                sc[dt][r] += bias_s[dt * 16 + lr - (w * 16 + 4 * lg + r) + 63];

        // online softmax (reduce across lr lanes via xor 1,2,4,8)
        #pragma unroll
        for (int r = 0; r < 4; ++r) {
            float mt = fmaxf(fmaxf(sc[0][r], sc[1][r]), fmaxf(sc[2][r], sc[3][r]));
            #pragma unroll
            for (int off = 1; off < 16; off <<= 1) mt = fmaxf(mt, __shfl_xor(mt, off, 64));
            float mn = fmaxf(m[r], mt);
            float scale = __expf(m[r] - mn);
            float rs = 0.f;
            #pragma unroll
            for (int dt = 0; dt < 4; ++dt) {
                float p = __expf(sc[dt][r] - mn);
                sc[dt][r] = p;
                rs += p;
            }
            #pragma unroll
            for (int off = 1; off < 16; off <<= 1) rs += __shfl_xor(rs, off, 64);
            l[r] = l[r] * scale + rs;
            m[r] = mn;
            #pragma unroll
            for (int dt = 0; dt < 4; ++dt) acc_o[dt][r] *= scale;
        }
        #pragma unroll
        for (int dt = 0; dt < 4; ++dt)
            #pragma unroll
            for (int r = 0; r < 4; ++r)
                Ps[w][(4 * lg + r) * 72 + dt * 16 + lr] = f2bf(sc[dt][r]);
        __syncthreads();

        // PV
        short8 pa0 = *(const short8*)(&Ps[w][lr * 72 + lg * 8]);
        short8 pa1 = *(const short8*)(&Ps[w][lr * 72 + 32 + lg * 8]);
        #pragma unroll
        for (int odt = 0; odt < 4; ++odt) {
            short8 bv0 = *(const short8*)(&Vst[(odt * 16 + lr) * 72 + lg * 8]);
            short8 bv1 = *(const short8*)(&Vst[(odt * 16 + lr) * 72 + 32 + lg * 8]);
            acc_o[odt] = __builtin_amdgcn_mfma_f32_16x16x32_bf16(pa0, bv0, acc_o[odt], 0, 0, 0);
            acc_o[odt] = __builtin_amdgcn_mfma_f32_16x16x32_bf16(pa1, bv1, acc_o[odt], 0, 0, 0);
        }
    }

    size_t orow_base = (size_t)(b * SS + q0 + w * 16);
    #pragma unroll
    for (int odt = 0; odt < 4; ++odt)
        #pragma unroll
        for (int r = 0; r < 4; ++r) {
            float v = acc_o[odt][r] / l[r];
            O[(orow_base + 4 * lg + r) * 1024 + h * 64 + odt * 16 + lr] = f2bf(v);
        }
}

// ---------------------------------------------------------------------------
extern "C" void kernel_launch(void* const* d_in, const int* in_sizes, int n_in,
                              void* d_out, int out_size, void* d_ws, size_t ws_size,
                              hipStream_t stream)
{
    const float* x   = (const float*)d_in[0];
    const float* Wq  = (const float*)d_in[1];
    const float* Wk  = (const float*)d_in[2];
    const float* Wv  = (const float*)d_in[3];
    const float* Wo  = (const float*)d_in[4];
    const float* ksc = (const float*)d_in[5];
    // d_in[6] (value_scale) intentionally unused — reference pools raw Wv
    const float* bias_emb = (const float*)d_in[7];
    float* out = (float*)d_out;

    char* ws = (char*)d_ws;
    // workspace layout (bytes)
    unsigned short* Wqk_h = (unsigned short*)(ws);                 // 1280*1024*2 = 2,621,440
    unsigned short* Wqk_l = (unsigned short*)(ws + 2621440);       // 2,621,440
    unsigned short* Wvb   = (unsigned short*)(ws + 5242880);       //  256*1024*2 =   524,288
    unsigned short* Wob   = (unsigned short*)(ws + 5767168);       // 1024*1024*2 = 2,097,152
    float*          tab   = (float*)(ws + 7864320);                // 16*4095*4   =   262,080 (+pad)
    unsigned short* Yh    = (unsigned short*)(ws + 8126464);       // 4096*1280*2 = 10,485,760
    unsigned short* Yl    = (unsigned short*)(ws + 18612224);      // 10,485,760
    unsigned short* Vb    = (unsigned short*)(ws + 29097984);      // 4096*256*2  =  2,097,152
    unsigned short* Ob    = (unsigned short*)(ws + 31195136);      // 4096*1024*2 =  8,388,608
    // total: 39,583,744 bytes

    prep_weights<<<2560, 256, 0, stream>>>(Wq, Wk, Wv, Wo, ksc, Wqk_h, Wqk_l, Wvb, Wob);
    build_bias<<<256, 256, 0, stream>>>(bias_emb, tab);

    // split-precision Q|K projection: [4096,1024] @ [1280,1024]^T -> Yh/Yl
    gemm_bt<2><<<dim3(10, 32), 256, 0, stream>>>(x, Wqk_h, Wqk_l, Yh, Yl, 4096, NQK, 1024);
    // V projection: [4096,1024] @ [256,1024]^T -> Vb bf16
    gemm_bt<1><<<dim3(2, 32), 256, 0, stream>>>(x, Wvb, nullptr, Vb, nullptr, 4096, 256, 1024);

    // flash attention: 32 q-tiles x 16 heads x 2 batches
    attn<<<1024, 256, 0, stream>>>(Yh, Yl, Vb, tab, Ob);

    // output projection: [4096,1024] @ [1024,1024]^T -> fp32 out
    gemm_bt<0><<<dim3(8, 32), 256, 0, stream>>>(Ob, Wob, nullptr, out, nullptr, 4096, 1024, 1024);
}

// Round 3
// 220.692 us; speedup vs baseline: 1.4423x; 1.4423x over previous
//
#include <hip/hip_runtime.h>

using half8 = __attribute__((ext_vector_type(8))) _Float16;
using half4 = __attribute__((ext_vector_type(4))) _Float16;
using f32x4 = __attribute__((ext_vector_type(4))) float;

#define BB 2
#define SS 2048
#define DD 1024
#define HH 16
#define KVH 4
#define HDIM 64
#define NQK 1280    // Q(1024) | K(256) columns of QK projection

// ---------------------------------------------------------------------------
// Prep: rows 0..1279 -> Wqk fp16 (Q direct, K pooled+key_scale).
// rows 1280..1535 -> pooled RAW V weights (value_scale unused: reference bug).
// rows 1536..2559 -> Wo fp16. grid 2560 x 256.
__global__ void prep_weights(const float* __restrict__ Wq, const float* __restrict__ Wk,
                             const float* __restrict__ Wv, const float* __restrict__ Wo,
                             const float* __restrict__ ksc,
                             _Float16* __restrict__ Wqk, _Float16* __restrict__ Wvb,
                             _Float16* __restrict__ Wob)
{
    int row = blockIdx.x;
    int c = threadIdx.x * 4;
    if (row < NQK) {
        if (row < 1024) {
            #pragma unroll
            for (int j = 0; j < 4; ++j)
                Wqk[(size_t)row * DD + c + j] = (_Float16)Wq[(size_t)row * DD + c + j];
        } else {
            int kh = row - 1024;                  // 0..255
            int kvi = kh >> 6, hd = kh & 63;
            #pragma unroll
            for (int j = 0; j < 4; ++j) {
                float s = 0.f;
                #pragma unroll
                for (int g = 0; g < 4; ++g)
                    s += Wk[(size_t)((kvi * 4 + g) * 64 + hd) * DD + c + j] * ksc[kvi * 4 + g];
                Wqk[(size_t)row * DD + c + j] = (_Float16)s;
            }
        }
    } else if (row < 1536) {
        int vh = row - 1280;
        int kvi = vh >> 6, hd = vh & 63;
        #pragma unroll
        for (int j = 0; j < 4; ++j) {
            float s = 0.f;
            #pragma unroll
            for (int g = 0; g < 4; ++g)
                s += Wv[(size_t)((kvi * 4 + g) * 64 + hd) * DD + c + j];
            Wvb[(size_t)vh * DD + c + j] = (_Float16)s;
        }
    } else {
        int r = row - 1536;
        #pragma unroll
        for (int j = 0; j < 4; ++j)
            Wob[(size_t)r * DD + c + j] = (_Float16)Wo[(size_t)r * DD + c + j];
    }
}

// Cast hidden_states fp32 -> fp16. grid 4096 x 256, 4 elems/thread.
__global__ void cast_x(const float* __restrict__ X, _Float16* __restrict__ Xh)
{
    int idx = (blockIdx.x * 256 + threadIdx.x) * 4;
    float4 v = *(const float4*)(X + idx);
    half4 o = { (_Float16)v.x, (_Float16)v.y, (_Float16)v.z, (_Float16)v.w };
    *(half4*)(Xh + idx) = o;
}

// T5 bucket via integer thresholds (matches numpy fp32 logf semantics at all
// integer rel positions; verified boundary cases 12/16/23/32/46/64/91).
__device__ __forceinline__ int rel_large(int rel) { // rel >= 8
    int n;
    if (rel < 12) n = 0; else if (rel < 16) n = 1; else if (rel < 23) n = 2;
    else if (rel < 32) n = 3; else if (rel < 46) n = 4; else if (rel < 64) n = 5;
    else if (rel < 91) n = 6; else if (rel < 128) n = 7; else n = 8;
    int large = 8 + n;
    return large > 15 ? 15 : large;
}

__global__ void build_bias(const float* __restrict__ bias_emb, float* __restrict__ tab)
{
    int idx = blockIdx.x * 256 + threadIdx.x;
    if (idx >= HH * 4095) return;
    int h = idx / 4095;
    int dpos = idx % 4095;
    int d = dpos - 2047;
    int rel = d < 0 ? -d : d;
    int bucket = (rel < 8) ? rel : rel_large(rel);
    if (d > 0) bucket += 16;
    tab[(size_t)h * 4095 + dpos] = bias_emb[bucket * HH + h];
}

// ---------------------------------------------------------------------------
// C[M,N] = A[M,K] @ B[N,K]^T, fp16 in, fp32 accum. 128x128 tile, BK=32,
// 4 waves (2x2), 4x4 16x16x32 frags.
// OUTK 0: C fp32.  OUTK 1: C fp16 row-major.  OUTK 2: C fp16 TRANSPOSED
// (Ct[col*M + row], used to pre-transpose V for scatter-free attn staging).
template<int OUTK>
__global__ __launch_bounds__(256) void gemm_bt(const _Float16* __restrict__ A,
                                               const _Float16* __restrict__ B,
                                               void* __restrict__ Cv,
                                               int M, int N, int K)
{
    __shared__ __align__(16) _Float16 As[128 * 40];
    __shared__ __align__(16) _Float16 Bs[128 * 40];
    int m0 = blockIdx.y * 128, n0 = blockIdx.x * 128;
    int t = threadIdx.x;
    int wv = t >> 6, lane = t & 63;
    int wm = wv >> 1, wn = wv & 1;
    int lr = lane & 15, lg = lane >> 4;
    f32x4 acc[4][4] = {};

    for (int k0 = 0; k0 < K; k0 += 32) {
        __syncthreads();
        #pragma unroll
        for (int it = 0; it < 2; ++it) {
            int idx = t + it * 256;
            int row = idx >> 2;
            int c = (idx & 3) << 3;
            *(uint4*)(&As[row * 40 + c]) = *(const uint4*)(A + (size_t)(m0 + row) * K + k0 + c);
            *(uint4*)(&Bs[row * 40 + c]) = *(const uint4*)(B + (size_t)(n0 + row) * K + k0 + c);
        }
        __syncthreads();
        half8 af[4], bfr[4];
        #pragma unroll
        for (int mi = 0; mi < 4; ++mi)
            af[mi] = *(const half8*)(&As[(wm * 64 + mi * 16 + lr) * 40 + lg * 8]);
        #pragma unroll
        for (int ni = 0; ni < 4; ++ni)
            bfr[ni] = *(const half8*)(&Bs[(wn * 64 + ni * 16 + lr) * 40 + lg * 8]);
        #pragma unroll
        for (int mi = 0; mi < 4; ++mi)
            #pragma unroll
            for (int ni = 0; ni < 4; ++ni)
                acc[mi][ni] = __builtin_amdgcn_mfma_f32_16x16x32_f16(af[mi], bfr[ni], acc[mi][ni], 0, 0, 0);
    }

    #pragma unroll
    for (int mi = 0; mi < 4; ++mi) {
        #pragma unroll
        for (int ni = 0; ni < 4; ++ni) {
            if constexpr (OUTK == 2) {
                int rowb = m0 + wm * 64 + mi * 16 + 4 * lg;
                int col  = n0 + wn * 64 + ni * 16 + lr;
                half4 o = { (_Float16)acc[mi][ni][0], (_Float16)acc[mi][ni][1],
                            (_Float16)acc[mi][ni][2], (_Float16)acc[mi][ni][3] };
                *(half4*)((_Float16*)Cv + (size_t)col * M + rowb) = o;
            } else {
                #pragma unroll
                for (int r = 0; r < 4; ++r) {
                    int row = m0 + wm * 64 + mi * 16 + 4 * lg + r;
                    int col = n0 + wn * 64 + ni * 16 + lr;
                    float v = acc[mi][ni][r];
                    if constexpr (OUTK == 0) ((float*)Cv)[(size_t)row * N + col] = v;
                    else                     ((_Float16*)Cv)[(size_t)row * N + col] = (_Float16)v;
                }
            }
        }
    }
}

// ---------------------------------------------------------------------------
// Flash attention, fp16. One block = 64 q-rows of one (b,h). 4 waves x 16 rows.
// K staged row-major [64][64] (stride 72) from Y; V staged [d][key] (stride 72)
// from PRE-TRANSPOSED Vt — vectorized copies, no scatter.
__global__ __launch_bounds__(256) void attn(const _Float16* __restrict__ Y,
                                            const _Float16* __restrict__ Vt,
                                            const float* __restrict__ tab,
                                            _Float16* __restrict__ O)
{
    int blk = blockIdx.x;
    int qb = blk & 31, h = (blk >> 5) & 15, b = blk >> 9;
    int kv = h >> 2;
    int q0 = qb * 64;
    int t = threadIdx.x, w = t >> 6, lane = t & 63, lr = lane & 15, lg = lane >> 4;

    __shared__ __align__(16) _Float16 Ks[64 * 72];
    __shared__ __align__(16) _Float16 Vst[64 * 72];
    __shared__ __align__(16) _Float16 Ps[4][16 * 72];
    __shared__ float bias_s[128];

    const size_t yoff = (size_t)(b * SS + q0 + w * 16 + lr) * NQK + h * 64;
    half8 aq0 = *(const half8*)(Y + yoff + lg * 8);
    half8 aq1 = *(const half8*)(Y + yoff + 32 + lg * 8);

    f32x4 acc_o[4] = {};
    float m[4], l[4];
    #pragma unroll
    for (int r = 0; r < 4; ++r) { m[r] = -1e30f; l[r] = 0.f; }

    for (int key0 = 0; key0 < SS; key0 += 64) {
        __syncthreads();
        #pragma unroll
        for (int it = 0; it < 2; ++it) {
            int idx = t + it * 256;
            int row = idx >> 3, c = (idx & 7) << 3;
            *(uint4*)(&Ks[row * 72 + c]) =
                *(const uint4*)(Y + (size_t)(b * SS + key0 + row) * NQK + 1024 + kv * 64 + c);
            *(uint4*)(&Vst[row * 72 + c]) =
                *(const uint4*)(Vt + (size_t)(kv * 64 + row) * 4096 + b * SS + key0 + c);
        }
        if (t < 128) {
            int ti = key0 - q0 + t - 63 + 2047;
            ti = ti < 0 ? 0 : (ti > 4094 ? 4094 : ti);
            bias_s[t] = tab[(size_t)h * 4095 + ti];
        }
        __syncthreads();

        // QK^T: scores D[i=4*lg+r][j=dt*16+lr]
        f32x4 z = {0.f, 0.f, 0.f, 0.f};
        f32x4 sc[4];
        __builtin_amdgcn_s_setprio(1);
        #pragma unroll
        for (int dt = 0; dt < 4; ++dt) {
            half8 bk0 = *(const half8*)(&Ks[(dt * 16 + lr) * 72 + lg * 8]);
            half8 bk1 = *(const half8*)(&Ks[(dt * 16 + lr) * 72 + 32 + lg * 8]);
            sc[dt] = __builtin_amdgcn_mfma_f32_16x16x32_f16(aq0, bk0, z, 0, 0, 0);
            sc[dt] = __builtin_amdgcn_mfma_f32_16x16x32_f16(aq1, bk1, sc[dt], 0, 0, 0);
        }
        __builtin_amdgcn_s_setprio(0);
        #pragma unroll
        for (int dt = 0; dt < 4; ++dt)
            #pragma unroll
            for (int r = 0; r < 4; ++r)
                sc[dt][r] += bias_s[dt * 16 + lr - (w * 16 + 4 * lg + r) + 63];

        // online softmax (reduce across lr lanes via xor 1,2,4,8)
        #pragma unroll
        for (int r = 0; r < 4; ++r) {
            float mt = fmaxf(fmaxf(sc[0][r], sc[1][r]), fmaxf(sc[2][r], sc[3][r]));
            #pragma unroll
            for (int off = 1; off < 16; off <<= 1) mt = fmaxf(mt, __shfl_xor(mt, off, 64));
            float mn = fmaxf(m[r], mt);
            float scale = __expf(m[r] - mn);
            float rs = 0.f;
            #pragma unroll
            for (int dt = 0; dt < 4; ++dt) {
                float p = __expf(sc[dt][r] - mn);
                sc[dt][r] = p;
                rs += p;
            }
            #pragma unroll
            for (int off = 1; off < 16; off <<= 1) rs += __shfl_xor(rs, off, 64);
            l[r] = l[r] * scale + rs;
            m[r] = mn;
            #pragma unroll
            for (int dt = 0; dt < 4; ++dt) acc_o[dt][r] *= scale;
        }
        #pragma unroll
        for (int dt = 0; dt < 4; ++dt)
            #pragma unroll
            for (int r = 0; r < 4; ++r)
                Ps[w][(4 * lg + r) * 72 + dt * 16 + lr] = (_Float16)sc[dt][r];
        __syncthreads();

        // PV: O[i][d] += P[i][j] V[j][d]  (B operand from d-major Vst)
        half8 pa0 = *(const half8*)(&Ps[w][lr * 72 + lg * 8]);
        half8 pa1 = *(const half8*)(&Ps[w][lr * 72 + 32 + lg * 8]);
        __builtin_amdgcn_s_setprio(1);
        #pragma unroll
        for (int odt = 0; odt < 4; ++odt) {
            half8 bv0 = *(const half8*)(&Vst[(odt * 16 + lr) * 72 + lg * 8]);
            half8 bv1 = *(const half8*)(&Vst[(odt * 16 + lr) * 72 + 32 + lg * 8]);
            acc_o[odt] = __builtin_amdgcn_mfma_f32_16x16x32_f16(pa0, bv0, acc_o[odt], 0, 0, 0);
            acc_o[odt] = __builtin_amdgcn_mfma_f32_16x16x32_f16(pa1, bv1, acc_o[odt], 0, 0, 0);
        }
        __builtin_amdgcn_s_setprio(0);
    }

    size_t orow_base = (size_t)(b * SS + q0 + w * 16);
    #pragma unroll
    for (int odt = 0; odt < 4; ++odt)
        #pragma unroll
        for (int r = 0; r < 4; ++r) {
            float v = acc_o[odt][r] / l[r];
            O[(orow_base + 4 * lg + r) * 1024 + h * 64 + odt * 16 + lr] = (_Float16)v;
        }
}

// ---------------------------------------------------------------------------
extern "C" void kernel_launch(void* const* d_in, const int* in_sizes, int n_in,
                              void* d_out, int out_size, void* d_ws, size_t ws_size,
                              hipStream_t stream)
{
    const float* x   = (const float*)d_in[0];
    const float* Wq  = (const float*)d_in[1];
    const float* Wk  = (const float*)d_in[2];
    const float* Wv  = (const float*)d_in[3];
    const float* Wo  = (const float*)d_in[4];
    const float* ksc = (const float*)d_in[5];
    // d_in[6] (value_scale) intentionally unused — reference pools raw Wv
    const float* bias_emb = (const float*)d_in[7];
    float* out = (float*)d_out;

    char* ws = (char*)d_ws;
    // workspace layout (bytes)
    _Float16* Wqk = (_Float16*)(ws);                  // 1280*1024*2 =  2,621,440
    _Float16* Wvb = (_Float16*)(ws + 2621440);        //  256*1024*2 =    524,288
    _Float16* Wob = (_Float16*)(ws + 3145728);        // 1024*1024*2 =  2,097,152
    float*    tab = (float*)(ws + 5242880);           // 16*4095*4   =    262,080 (+pad)
    _Float16* Xh  = (_Float16*)(ws + 5505024);        // 4096*1024*2 =  8,388,608
    _Float16* Y   = (_Float16*)(ws + 13893632);       // 4096*1280*2 = 10,485,760
    _Float16* Vt  = (_Float16*)(ws + 24379392);       //  256*4096*2 =  2,097,152
    _Float16* Ob  = (_Float16*)(ws + 26476544);       // 4096*1024*2 =  8,388,608
    // total: 34,865,152 bytes

    prep_weights<<<2560, 256, 0, stream>>>(Wq, Wk, Wv, Wo, ksc, Wqk, Wvb, Wob);
    cast_x<<<4096, 256, 0, stream>>>(x, Xh);
    build_bias<<<256, 256, 0, stream>>>(bias_emb, tab);

    // Q|K projection: [4096,1024] @ [1280,1024]^T -> Y fp16
    gemm_bt<1><<<dim3(10, 32), 256, 0, stream>>>(Xh, Wqk, Y, 4096, NQK, 1024);
    // V projection, TRANSPOSED output: [4096,1024] @ [256,1024]^T -> Vt[256][4096]
    gemm_bt<2><<<dim3(2, 32), 256, 0, stream>>>(Xh, Wvb, Vt, 4096, 256, 1024);

    // flash attention: 32 q-tiles x 16 heads x 2 batches
    attn<<<1024, 256, 0, stream>>>(Y, Vt, tab, Ob);

    // output projection: [4096,1024] @ [1024,1024]^T -> fp32 out
    gemm_bt<0><<<dim3(8, 32), 256, 0, stream>>>(Ob, Wob, out, 4096, 1024, 1024);
}

// Round 4
// 162.786 us; speedup vs baseline: 1.9553x; 1.3557x over previous
//
#include <hip/hip_runtime.h>

using half8 = __attribute__((ext_vector_type(8))) _Float16;
using half4 = __attribute__((ext_vector_type(4))) _Float16;
using f32x4 = __attribute__((ext_vector_type(4))) float;

#define BB 2
#define SS 2048
#define DD 1024
#define HH 16
#define KVH 4
#define HDIM 64
#define NQK 1280    // Q(1024) | K(256) columns of QK projection

// async global->LDS, 16B per lane, linear LDS dest (wave-uniform base + lane*16)
#define GLDS(g, l) __builtin_amdgcn_global_load_lds( \
    (const __attribute__((address_space(1))) void*)(g), \
    (__attribute__((address_space(3))) void*)(l), 16, 0, 0)

__device__ __forceinline__ f32x4 mfma16(half4 a, half4 b, f32x4 c) {
#if __has_builtin(__builtin_amdgcn_mfma_f32_16x16x16_f16)
    return __builtin_amdgcn_mfma_f32_16x16x16_f16(a, b, c, 0, 0, 0);
#else
    return __builtin_amdgcn_mfma_f32_16x16x16f16(a, b, c, 0, 0, 0);
#endif
}

// ---------------------------------------------------------------------------
// Prep: rows 0..1279 -> Wqk fp16 (Q direct, K pooled+key_scale).
// rows 1280..1535 -> pooled RAW V weights (value_scale unused: reference bug).
// rows 1536..2559 -> Wo fp16. grid 2560 x 256.
__global__ void prep_weights(const float* __restrict__ Wq, const float* __restrict__ Wk,
                             const float* __restrict__ Wv, const float* __restrict__ Wo,
                             const float* __restrict__ ksc,
                             _Float16* __restrict__ Wqk, _Float16* __restrict__ Wvb,
                             _Float16* __restrict__ Wob)
{
    int row = blockIdx.x;
    int c = threadIdx.x * 4;
    if (row < NQK) {
        if (row < 1024) {
            #pragma unroll
            for (int j = 0; j < 4; ++j)
                Wqk[(size_t)row * DD + c + j] = (_Float16)Wq[(size_t)row * DD + c + j];
        } else {
            int kh = row - 1024;                  // 0..255
            int kvi = kh >> 6, hd = kh & 63;
            #pragma unroll
            for (int j = 0; j < 4; ++j) {
                float s = 0.f;
                #pragma unroll
                for (int g = 0; g < 4; ++g)
                    s += Wk[(size_t)((kvi * 4 + g) * 64 + hd) * DD + c + j] * ksc[kvi * 4 + g];
                Wqk[(size_t)row * DD + c + j] = (_Float16)s;
            }
        }
    } else if (row < 1536) {
        int vh = row - 1280;
        int kvi = vh >> 6, hd = vh & 63;
        #pragma unroll
        for (int j = 0; j < 4; ++j) {
            float s = 0.f;
            #pragma unroll
            for (int g = 0; g < 4; ++g)
                s += Wv[(size_t)((kvi * 4 + g) * 64 + hd) * DD + c + j];
            Wvb[(size_t)vh * DD + c + j] = (_Float16)s;
        }
    } else {
        int r = row - 1536;
        #pragma unroll
        for (int j = 0; j < 4; ++j)
            Wob[(size_t)r * DD + c + j] = (_Float16)Wo[(size_t)r * DD + c + j];
    }
}

// Cast hidden_states fp32 -> fp16. grid 4096 x 256, 4 elems/thread.
__global__ void cast_x(const float* __restrict__ X, _Float16* __restrict__ Xh)
{
    int idx = (blockIdx.x * 256 + threadIdx.x) * 4;
    float4 v = *(const float4*)(X + idx);
    half4 o = { (_Float16)v.x, (_Float16)v.y, (_Float16)v.z, (_Float16)v.w };
    *(half4*)(Xh + idx) = o;
}

// T5 bucket via integer thresholds (matches numpy fp32 logf semantics at all
// integer rel positions; verified boundary cases 12/16/23/32/46/64/91).
__device__ __forceinline__ int rel_large(int rel) { // rel >= 8
    int n;
    if (rel < 12) n = 0; else if (rel < 16) n = 1; else if (rel < 23) n = 2;
    else if (rel < 32) n = 3; else if (rel < 46) n = 4; else if (rel < 64) n = 5;
    else if (rel < 91) n = 6; else if (rel < 128) n = 7; else n = 8;
    int large = 8 + n;
    return large > 15 ? 15 : large;
}

__global__ void build_bias(const float* __restrict__ bias_emb, float* __restrict__ tab)
{
    int idx = blockIdx.x * 256 + threadIdx.x;
    if (idx >= HH * 4095) return;
    int h = idx / 4095;
    int dpos = idx % 4095;
    int d = dpos - 2047;
    int rel = d < 0 ? -d : d;
    int bucket = (rel < 8) ? rel : rel_large(rel);
    if (d > 0) bucket += 16;
    tab[(size_t)h * 4095 + dpos] = bias_emb[bucket * HH + h];
}

// ---------------------------------------------------------------------------
// C = A[M,K] @ B[N,K]^T, fp16 in, fp32 accum. 128x128 tile, BK=32, 4 waves,
// global_load_lds staging into linear [128][32] LDS (m97 structure).
// OUTK 0: C0 fp32 row-major (ldc stride).
// OUTK 3: fused projection output: cols < 1280 -> C0 fp16 row-major (ldc);
//         cols >= 1280 -> C1 fp16 TRANSPOSED (C1[(col-1280)*M + row]).
template<int OUTK>
__global__ __launch_bounds__(256) void gemm_bt(const _Float16* __restrict__ A,
                                               const _Float16* __restrict__ B,
                                               void* __restrict__ C0,
                                               _Float16* __restrict__ C1,
                                               int M, int K, int ldc)
{
    __shared__ __align__(16) _Float16 As[128 * 32];
    __shared__ __align__(16) _Float16 Bs[128 * 32];
    int m0 = blockIdx.y * 128, n0 = blockIdx.x * 128;
    int t = threadIdx.x;
    int wv = t >> 6, lane = t & 63;
    int wm = wv >> 1, wn = wv & 1;
    int lr = lane & 15, lg = lane >> 4;
    int srow = lane >> 2;            // 0..15 within chunk
    int scol = (lane & 3) << 3;      // 0,8,16,24 halves
    f32x4 acc[4][4] = {};

    for (int k0 = 0; k0 < K; k0 += 32) {
        __syncthreads();   // prev-tile readers done
        #pragma unroll
        for (int i = 0; i < 2; ++i) {
            int chunk = wv * 2 + i;            // 0..7 (16 rows each)
            int row = chunk * 16 + srow;
            GLDS(A + (size_t)(m0 + row) * K + k0 + scol, As + chunk * 512 + lane * 8);
            GLDS(B + (size_t)(n0 + row) * K + k0 + scol, Bs + chunk * 512 + lane * 8);
        }
        __syncthreads();   // compiler drains vmcnt before barrier -> LDS ready
        half8 af[4], bfr[4];
        #pragma unroll
        for (int mi = 0; mi < 4; ++mi)
            af[mi] = *(const half8*)(&As[(wm * 64 + mi * 16 + lr) * 32 + lg * 8]);
        #pragma unroll
        for (int ni = 0; ni < 4; ++ni)
            bfr[ni] = *(const half8*)(&Bs[(wn * 64 + ni * 16 + lr) * 32 + lg * 8]);
        __builtin_amdgcn_s_setprio(1);
        #pragma unroll
        for (int mi = 0; mi < 4; ++mi)
            #pragma unroll
            for (int ni = 0; ni < 4; ++ni)
                acc[mi][ni] = __builtin_amdgcn_mfma_f32_16x16x32_f16(af[mi], bfr[ni], acc[mi][ni], 0, 0, 0);
        __builtin_amdgcn_s_setprio(0);
    }

    #pragma unroll
    for (int mi = 0; mi < 4; ++mi) {
        #pragma unroll
        for (int ni = 0; ni < 4; ++ni) {
            int rowb = m0 + wm * 64 + mi * 16 + 4 * lg;
            int col  = n0 + wn * 64 + ni * 16 + lr;
            if constexpr (OUTK == 0) {
                #pragma unroll
                for (int r = 0; r < 4; ++r)
                    ((float*)C0)[(size_t)(rowb + r) * ldc + col] = acc[mi][ni][r];
            } else {
                if (n0 < 1280) {
                    #pragma unroll
                    for (int r = 0; r < 4; ++r)
                        ((_Float16*)C0)[(size_t)(rowb + r) * ldc + col] = (_Float16)acc[mi][ni][r];
                } else {
                    half4 o = { (_Float16)acc[mi][ni][0], (_Float16)acc[mi][ni][1],
                                (_Float16)acc[mi][ni][2], (_Float16)acc[mi][ni][3] };
                    *(half4*)(C1 + (size_t)(col - 1280) * M + rowb) = o;
                }
            }
        }
    }
}

// ---------------------------------------------------------------------------
// Flash attention, swapped-operand QK^T (P lane-local), fp16.
// One block = 64 q-rows of one (b,h); wave w owns q-rows w*16..w*16+15,
// lane's q-row = lr. QK: sc[dt] = mfma(K_frag, Q_frag) -> lane holds
// P[q=lr][key=dt*16+4*lg+r]. That layout IS the 16x16x16 B-fragment, so PV
// runs from registers: acc_o[odt] += mfma16(Vt_frag, P_frag). No P LDS
// roundtrip, 2 barriers/tile, scalar per-lane softmax state.
__global__ __launch_bounds__(256) void attn(const _Float16* __restrict__ Y,
                                            const _Float16* __restrict__ Vt,
                                            const float* __restrict__ tab,
                                            _Float16* __restrict__ O)
{
    int blk = blockIdx.x;
    int qb = blk & 31, h = (blk >> 5) & 15, b = blk >> 9;
    int kv = h >> 2;
    int q0 = qb * 64;
    int t = threadIdx.x, w = t >> 6, lane = t & 63, lr = lane & 15, lg = lane >> 4;

    __shared__ __align__(16) _Float16 Ks[64 * 72];
    __shared__ __align__(16) _Float16 Vst[64 * 72];
    __shared__ float bias_s[128];

    const size_t yoff = (size_t)(b * SS + q0 + w * 16 + lr) * NQK + h * 64;
    half8 aq0 = *(const half8*)(Y + yoff + lg * 8);
    half8 aq1 = *(const half8*)(Y + yoff + 32 + lg * 8);

    f32x4 acc_o[4] = {};
    float m = -1e30f, l = 0.f;
    const int bb = 63 - w * 16 - lr + 4 * lg;   // bias base: + dt*16 + r

    for (int key0 = 0; key0 < SS; key0 += 64) {
        __syncthreads();
        #pragma unroll
        for (int it = 0; it < 2; ++it) {
            int idx = t + it * 256;
            int row = idx >> 3, c = (idx & 7) << 3;
            *(uint4*)(&Ks[row * 72 + c]) =
                *(const uint4*)(Y + (size_t)(b * SS + key0 + row) * NQK + 1024 + kv * 64 + c);
            *(uint4*)(&Vst[row * 72 + c]) =
                *(const uint4*)(Vt + (size_t)(kv * 64 + row) * 4096 + b * SS + key0 + c);
        }
        if (t < 128) {
            int ti = key0 - q0 + t - 63 + 2047;
            ti = ti < 0 ? 0 : (ti > 4094 ? 4094 : ti);
            bias_s[t] = tab[(size_t)h * 4095 + ti];
        }
        __syncthreads();

        // swapped QK^T: sc[dt][r] = S[key=key0+dt*16+4lg+r][q=lr]
        f32x4 z = {0.f, 0.f, 0.f, 0.f};
        f32x4 sc[4];
        __builtin_amdgcn_s_setprio(1);
        #pragma unroll
        for (int dt = 0; dt < 4; ++dt) {
            half8 bk0 = *(const half8*)(&Ks[(dt * 16 + lr) * 72 + lg * 8]);
            half8 bk1 = *(const half8*)(&Ks[(dt * 16 + lr) * 72 + 32 + lg * 8]);
            sc[dt] = __builtin_amdgcn_mfma_f32_16x16x32_f16(bk0, aq0, z, 0, 0, 0);
            sc[dt] = __builtin_amdgcn_mfma_f32_16x16x32_f16(bk1, aq1, sc[dt], 0, 0, 0);
        }
        __builtin_amdgcn_s_setprio(0);

        // + relative position bias (consecutive r -> consecutive idx)
        #pragma unroll
        for (int dt = 0; dt < 4; ++dt)
            #pragma unroll
            for (int r = 0; r < 4; ++r)
                sc[dt][r] += bias_s[bb + dt * 16 + r];

        // per-lane online softmax for q-row lr (partners at lane^16, lane^32)
        float pmax = sc[0][0];
        #pragma unroll
        for (int dt = 0; dt < 4; ++dt)
            #pragma unroll
            for (int r = 0; r < 4; ++r) pmax = fmaxf(pmax, sc[dt][r]);
        pmax = fmaxf(pmax, __shfl_xor(pmax, 16, 64));
        pmax = fmaxf(pmax, __shfl_xor(pmax, 32, 64));
        float mn = fmaxf(m, pmax);
        float scale = __expf(m - mn);
        float rs = 0.f;
        #pragma unroll
        for (int dt = 0; dt < 4; ++dt)
            #pragma unroll
            for (int r = 0; r < 4; ++r) {
                float p = __expf(sc[dt][r] - mn);
                sc[dt][r] = p;
                rs += p;
            }
        rs += __shfl_xor(rs, 16, 64);
        rs += __shfl_xor(rs, 32, 64);
        l = l * scale + rs;
        m = mn;
        #pragma unroll
        for (int odt = 0; odt < 4; ++odt)
            #pragma unroll
            for (int r = 0; r < 4; ++r) acc_o[odt][r] *= scale;

        // pack P to fp16 B-fragments for 16x16x16 MFMA (k=4*lg+e matches!)
        half4 pf[4];
        #pragma unroll
        for (int dt = 0; dt < 4; ++dt)
            pf[dt] = { (_Float16)sc[dt][0], (_Float16)sc[dt][1],
                       (_Float16)sc[dt][2], (_Float16)sc[dt][3] };

        // PV: acc_o[odt] (= O^T[d=odt*16+4lg+r][q=lr]) += V^T frag x P frag
        __builtin_amdgcn_s_setprio(1);
        #pragma unroll
        for (int odt = 0; odt < 4; ++odt)
            #pragma unroll
            for (int dt = 0; dt < 4; ++dt) {
                half4 vf = *(const half4*)(&Vst[(odt * 16 + lr) * 72 + dt * 16 + 4 * lg]);
                acc_o[odt] = mfma16(vf, pf[dt], acc_o[odt]);
            }
        __builtin_amdgcn_s_setprio(0);
    }

    // epilogue: lane writes its q-row, d = odt*16 + 4*lg + r (half4 stores)
    float inv = 1.f / l;
    _Float16* orow = O + (size_t)(b * SS + q0 + w * 16 + lr) * 1024 + h * 64;
    #pragma unroll
    for (int odt = 0; odt < 4; ++odt) {
        half4 o = { (_Float16)(acc_o[odt][0] * inv), (_Float16)(acc_o[odt][1] * inv),
                    (_Float16)(acc_o[odt][2] * inv), (_Float16)(acc_o[odt][3] * inv) };
        *(half4*)(orow + odt * 16 + 4 * lg) = o;
    }
}

// ---------------------------------------------------------------------------
extern "C" void kernel_launch(void* const* d_in, const int* in_sizes, int n_in,
                              void* d_out, int out_size, void* d_ws, size_t ws_size,
                              hipStream_t stream)
{
    const float* x   = (const float*)d_in[0];
    const float* Wq  = (const float*)d_in[1];
    const float* Wk  = (const float*)d_in[2];
    const float* Wv  = (const float*)d_in[3];
    const float* Wo  = (const float*)d_in[4];
    const float* ksc = (const float*)d_in[5];
    // d_in[6] (value_scale) intentionally unused — reference pools raw Wv
    const float* bias_emb = (const float*)d_in[7];
    float* out = (float*)d_out;

    char* ws = (char*)d_ws;
    // workspace layout (bytes); Wqk and Wvb MUST be adjacent (fused GEMM B)
    _Float16* Wqk = (_Float16*)(ws);                  // 1280*1024*2 =  2,621,440
    _Float16* Wvb = (_Float16*)(ws + 2621440);        //  256*1024*2 =    524,288
    _Float16* Wob = (_Float16*)(ws + 3145728);        // 1024*1024*2 =  2,097,152
    float*    tab = (float*)(ws + 5242880);           // 16*4095*4   =    262,080 (+pad)
    _Float16* Xh  = (_Float16*)(ws + 5505024);        // 4096*1024*2 =  8,388,608
    _Float16* Y   = (_Float16*)(ws + 13893632);       // 4096*1280*2 = 10,485,760
    _Float16* Vt  = (_Float16*)(ws + 24379392);       //  256*4096*2 =  2,097,152
    _Float16* Ob  = (_Float16*)(ws + 26476544);       // 4096*1024*2 =  8,388,608
    // total: 34,865,152 bytes

    prep_weights<<<2560, 256, 0, stream>>>(Wq, Wk, Wv, Wo, ksc, Wqk, Wvb, Wob);
    cast_x<<<4096, 256, 0, stream>>>(x, Xh);
    build_bias<<<256, 256, 0, stream>>>(bias_emb, tab);

    // fused Q|K|V projection: [4096,1024] @ [1536,1024]^T
    // cols 0..1279 -> Y row-major; cols 1280..1535 -> Vt transposed
    gemm_bt<3><<<dim3(12, 32), 256, 0, stream>>>(Xh, Wqk, Y, Vt, 4096, 1024, NQK);

    // flash attention: 32 q-tiles x 16 heads x 2 batches
    attn<<<1024, 256, 0, stream>>>(Y, Vt, tab, Ob);

    // output projection: [4096,1024] @ [1024,1024]^T -> fp32 out
    gemm_bt<0><<<dim3(8, 32), 256, 0, stream>>>(Ob, Wob, out, nullptr, 4096, 1024, 1024);
}

// Round 5
// 144.990 us; speedup vs baseline: 2.1953x; 1.1227x over previous
//
#include <hip/hip_runtime.h>

using half8 = __attribute__((ext_vector_type(8))) _Float16;
using half4 = __attribute__((ext_vector_type(4))) _Float16;
using f32x4 = __attribute__((ext_vector_type(4))) float;

#define BB 2
#define SS 2048
#define DD 1024
#define HH 16
#define KVH 4
#define HDIM 64
#define NQK 1280    // Q(1024) | K(256) columns of QK projection

// async global->LDS, 16B per lane, linear LDS dest (wave-uniform base + lane*16)
#define GLDS(g, l) __builtin_amdgcn_global_load_lds( \
    (const __attribute__((address_space(1))) void*)(g), \
    (__attribute__((address_space(3))) void*)(l), 16, 0, 0)

__device__ __forceinline__ f32x4 mfma16(half4 a, half4 b, f32x4 c) {
    return __builtin_amdgcn_mfma_f32_16x16x16f16(a, b, c, 0, 0, 0);
}

// ---------------------------------------------------------------------------
// Prep: rows 0..1279 -> Wqk fp16 (Q direct, K pooled+key_scale).
// rows 1280..1535 -> pooled RAW V weights (value_scale unused: reference bug).
// rows 1536..2559 -> Wo fp16. grid 2560 x 256.
__global__ void prep_weights(const float* __restrict__ Wq, const float* __restrict__ Wk,
                             const float* __restrict__ Wv, const float* __restrict__ Wo,
                             const float* __restrict__ ksc,
                             _Float16* __restrict__ Wqk, _Float16* __restrict__ Wvb,
                             _Float16* __restrict__ Wob)
{
    int row = blockIdx.x;
    int c = threadIdx.x * 4;
    if (row < NQK) {
        if (row < 1024) {
            #pragma unroll
            for (int j = 0; j < 4; ++j)
                Wqk[(size_t)row * DD + c + j] = (_Float16)Wq[(size_t)row * DD + c + j];
        } else {
            int kh = row - 1024;                  // 0..255
            int kvi = kh >> 6, hd = kh & 63;
            #pragma unroll
            for (int j = 0; j < 4; ++j) {
                float s = 0.f;
                #pragma unroll
                for (int g = 0; g < 4; ++g)
                    s += Wk[(size_t)((kvi * 4 + g) * 64 + hd) * DD + c + j] * ksc[kvi * 4 + g];
                Wqk[(size_t)row * DD + c + j] = (_Float16)s;
            }
        }
    } else if (row < 1536) {
        int vh = row - 1280;
        int kvi = vh >> 6, hd = vh & 63;
        #pragma unroll
        for (int j = 0; j < 4; ++j) {
            float s = 0.f;
            #pragma unroll
            for (int g = 0; g < 4; ++g)
                s += Wv[(size_t)((kvi * 4 + g) * 64 + hd) * DD + c + j];
            Wvb[(size_t)vh * DD + c + j] = (_Float16)s;
        }
    } else {
        int r = row - 1536;
        #pragma unroll
        for (int j = 0; j < 4; ++j)
            Wob[(size_t)r * DD + c + j] = (_Float16)Wo[(size_t)r * DD + c + j];
    }
}

// Cast hidden_states fp32 -> fp16. grid 4096 x 256, 4 elems/thread.
__global__ void cast_x(const float* __restrict__ X, _Float16* __restrict__ Xh)
{
    int idx = (blockIdx.x * 256 + threadIdx.x) * 4;
    float4 v = *(const float4*)(X + idx);
    half4 o = { (_Float16)v.x, (_Float16)v.y, (_Float16)v.z, (_Float16)v.w };
    *(half4*)(Xh + idx) = o;
}

// T5 bucket via integer thresholds (matches numpy fp32 logf semantics at all
// integer rel positions; verified boundary cases 12/16/23/32/46/64/91).
__device__ __forceinline__ int rel_large(int rel) { // rel >= 8
    int n;
    if (rel < 12) n = 0; else if (rel < 16) n = 1; else if (rel < 23) n = 2;
    else if (rel < 32) n = 3; else if (rel < 46) n = 4; else if (rel < 64) n = 5;
    else if (rel < 91) n = 6; else if (rel < 128) n = 7; else n = 8;
    int large = 8 + n;
    return large > 15 ? 15 : large;
}

__global__ void build_bias(const float* __restrict__ bias_emb, float* __restrict__ tab)
{
    int idx = blockIdx.x * 256 + threadIdx.x;
    if (idx >= HH * 4095) return;
    int h = idx / 4095;
    int dpos = idx % 4095;
    int d = dpos - 2047;
    int rel = d < 0 ? -d : d;
    int bucket = (rel < 8) ? rel : rel_large(rel);
    if (d > 0) bucket += 16;
    tab[(size_t)h * 4095 + dpos] = bias_emb[bucket * HH + h];
}

// ---------------------------------------------------------------------------
// C = A[M,K] @ B[N,K]^T, fp16 in, fp32 accum. 128x128 tile, BK=32, 4 waves,
// global_load_lds staging into linear [128][32] LDS (m97 structure).
// OUTK 0: C0 fp32 row-major (ldc stride).
// OUTK 3: fused projection output: cols < 1280 -> C0 fp16 row-major (ldc);
//         cols >= 1280 -> C1 fp16 TRANSPOSED (C1[(col-1280)*M + row]).
template<int OUTK>
__global__ __launch_bounds__(256) void gemm_bt(const _Float16* __restrict__ A,
                                               const _Float16* __restrict__ B,
                                               void* __restrict__ C0,
                                               _Float16* __restrict__ C1,
                                               int M, int K, int ldc)
{
    __shared__ __align__(16) _Float16 As[128 * 32];
    __shared__ __align__(16) _Float16 Bs[128 * 32];
    int m0 = blockIdx.y * 128, n0 = blockIdx.x * 128;
    int t = threadIdx.x;
    int wv = t >> 6, lane = t & 63;
    int wm = wv >> 1, wn = wv & 1;
    int lr = lane & 15, lg = lane >> 4;
    int srow = lane >> 2;            // 0..15 within chunk
    int scol = (lane & 3) << 3;      // 0,8,16,24 halves
    f32x4 acc[4][4] = {};

    for (int k0 = 0; k0 < K; k0 += 32) {
        __syncthreads();   // prev-tile readers done
        #pragma unroll
        for (int i = 0; i < 2; ++i) {
            int chunk = wv * 2 + i;            // 0..7 (16 rows each)
            int row = chunk * 16 + srow;
            GLDS(A + (size_t)(m0 + row) * K + k0 + scol, As + chunk * 512 + lane * 8);
            GLDS(B + (size_t)(n0 + row) * K + k0 + scol, Bs + chunk * 512 + lane * 8);
        }
        __syncthreads();   // compiler drains vmcnt before barrier -> LDS ready
        half8 af[4], bfr[4];
        #pragma unroll
        for (int mi = 0; mi < 4; ++mi)
            af[mi] = *(const half8*)(&As[(wm * 64 + mi * 16 + lr) * 32 + lg * 8]);
        #pragma unroll
        for (int ni = 0; ni < 4; ++ni)
            bfr[ni] = *(const half8*)(&Bs[(wn * 64 + ni * 16 + lr) * 32 + lg * 8]);
        __builtin_amdgcn_s_setprio(1);
        #pragma unroll
        for (int mi = 0; mi < 4; ++mi)
            #pragma unroll
            for (int ni = 0; ni < 4; ++ni)
                acc[mi][ni] = __builtin_amdgcn_mfma_f32_16x16x32_f16(af[mi], bfr[ni], acc[mi][ni], 0, 0, 0);
        __builtin_amdgcn_s_setprio(0);
    }

    #pragma unroll
    for (int mi = 0; mi < 4; ++mi) {
        #pragma unroll
        for (int ni = 0; ni < 4; ++ni) {
            int rowb = m0 + wm * 64 + mi * 16 + 4 * lg;
            int col  = n0 + wn * 64 + ni * 16 + lr;
            if constexpr (OUTK == 0) {
                #pragma unroll
                for (int r = 0; r < 4; ++r)
                    ((float*)C0)[(size_t)(rowb + r) * ldc + col] = acc[mi][ni][r];
            } else {
                if (n0 < 1280) {
                    #pragma unroll
                    for (int r = 0; r < 4; ++r)
                        ((_Float16*)C0)[(size_t)(rowb + r) * ldc + col] = (_Float16)acc[mi][ni][r];
                } else {
                    half4 o = { (_Float16)acc[mi][ni][0], (_Float16)acc[mi][ni][1],
                                (_Float16)acc[mi][ni][2], (_Float16)acc[mi][ni][3] };
                    *(half4*)(C1 + (size_t)(col - 1280) * M + rowb) = o;
                }
            }
        }
    }
}

// ---------------------------------------------------------------------------
// Flash attention, swapped-operand QK^T, fp16, double-buffered async staging.
// One block = 64 q-rows of one (b,h); lane's q-row = lr (partners ^16, ^32).
// Per tile: issue next K/V global loads -> regs; compute (QK, softmax, PV)
// on current LDS buffer; ds_write regs -> alternate buffer; ONE barrier.
// Far tiles (|key0-q0| >= 192): rel-pos bucket saturated -> uniform bias,
// folded into the softmax offset (no per-element bias loads/adds).
__global__ __launch_bounds__(256) void attn(const _Float16* __restrict__ Y,
                                            const _Float16* __restrict__ Vt,
                                            const float* __restrict__ tab,
                                            _Float16* __restrict__ O)
{
    // bijective XCD swizzle: blocks sharing a (b,kv) K/V slab (128 consecutive
    // logical ids) land on one XCD's L2. 1024 = 8 * 128 exactly.
    int blk = (blockIdx.x & 7) * 128 + (blockIdx.x >> 3);
    int qb = blk & 31, h = (blk >> 5) & 15, b = blk >> 9;
    int kv = h >> 2;
    int q0 = qb * 64;
    int t = threadIdx.x, w = t >> 6, lane = t & 63, lr = lane & 15, lg = lane >> 4;

    __shared__ __align__(16) _Float16 Ks[2][64 * 72];
    __shared__ __align__(16) _Float16 Vst[2][64 * 72];
    __shared__ float bias_s[2][128];

    const size_t yoff = (size_t)(b * SS + q0 + w * 16 + lr) * NQK + h * 64;
    half8 aq0 = *(const half8*)(Y + yoff + lg * 8);
    half8 aq1 = *(const half8*)(Y + yoff + 32 + lg * 8);

    // far-tile uniform bias values (bucket saturated at |d|>=128)
    const float bias_neg = tab[(size_t)h * 4095 + 0];      // key << q
    const float bias_pos = tab[(size_t)h * 4095 + 4094];   // key >> q

    f32x4 acc_o[4] = {};
    float m = -1e30f, l = 0.f;
    const int bb = 63 - w * 16 - lr + 4 * lg;   // bias base: + dt*16 + r

    // staging registers
    uint4 kreg0, kreg1, vreg0, vreg1;
    float breg = 0.f;
    const int srow = t >> 3, sc8 = (t & 7) << 3;        // chunk 0: rows 0..31
    const int srow1 = srow + 32;                        // chunk 1: rows 32..63

#define ATTN_LOAD(KEY0)                                                          \
    {                                                                            \
        int k0_ = (KEY0);                                                        \
        kreg0 = *(const uint4*)(Y + (size_t)(b * SS + k0_ + srow)  * NQK + 1024 + kv * 64 + sc8); \
        kreg1 = *(const uint4*)(Y + (size_t)(b * SS + k0_ + srow1) * NQK + 1024 + kv * 64 + sc8); \
        vreg0 = *(const uint4*)(Vt + (size_t)(kv * 64 + srow)  * 4096 + b * SS + k0_ + sc8); \
        vreg1 = *(const uint4*)(Vt + (size_t)(kv * 64 + srow1) * 4096 + b * SS + k0_ + sc8); \
        bool far_ = (k0_ >= q0 + 192) || (k0_ <= q0 - 192);                      \
        if (!far_ && t < 128) {                                                  \
            int ti = k0_ - q0 + t - 63 + 2047;                                   \
            ti = ti < 0 ? 0 : (ti > 4094 ? 4094 : ti);                           \
            breg = tab[(size_t)h * 4095 + ti];                                   \
        }                                                                        \
    }

#define ATTN_WRITE(BUF, KEY0)                                                    \
    {                                                                            \
        int bf_ = (BUF);                                                         \
        *(uint4*)(&Ks[bf_][srow  * 72 + sc8]) = kreg0;                           \
        *(uint4*)(&Ks[bf_][srow1 * 72 + sc8]) = kreg1;                           \
        *(uint4*)(&Vst[bf_][srow  * 72 + sc8]) = vreg0;                          \
        *(uint4*)(&Vst[bf_][srow1 * 72 + sc8]) = vreg1;                          \
        bool far_ = ((KEY0) >= q0 + 192) || ((KEY0) <= q0 - 192);                \
        if (!far_ && t < 128) bias_s[bf_][t] = breg;                             \
    }

    ATTN_LOAD(0);
    ATTN_WRITE(0, 0);
    __syncthreads();
    int cur = 0;

    for (int key0 = 0; key0 < SS; key0 += 64) {
        if (key0 + 64 < SS) ATTN_LOAD(key0 + 64);   // async: regs used only in WRITE

        const _Float16* ks = Ks[cur];
        const _Float16* vs = Vst[cur];
        bool far = (key0 >= q0 + 192) || (key0 <= q0 - 192);

        // swapped QK^T: sc[dt][r] = S[key=key0+dt*16+4lg+r][q=lr]
        f32x4 z = {0.f, 0.f, 0.f, 0.f};
        f32x4 sc[4];
        __builtin_amdgcn_s_setprio(1);
        #pragma unroll
        for (int dt = 0; dt < 4; ++dt) {
            half8 bk0 = *(const half8*)(&ks[(dt * 16 + lr) * 72 + lg * 8]);
            half8 bk1 = *(const half8*)(&ks[(dt * 16 + lr) * 72 + 32 + lg * 8]);
            sc[dt] = __builtin_amdgcn_mfma_f32_16x16x32_f16(bk0, aq0, z, 0, 0, 0);
            sc[dt] = __builtin_amdgcn_mfma_f32_16x16x32_f16(bk1, aq1, sc[dt], 0, 0, 0);
        }
        __builtin_amdgcn_s_setprio(0);

        float c;
        if (!far) {
            #pragma unroll
            for (int dt = 0; dt < 4; ++dt)
                #pragma unroll
                for (int r = 0; r < 4; ++r)
                    sc[dt][r] += bias_s[cur][bb + dt * 16 + r];
            c = 0.f;
        } else {
            c = (key0 > q0) ? bias_pos : bias_neg;
        }

        // per-lane online softmax with deferred rescale (THR=8)
        float pmax = sc[0][0];
        #pragma unroll
        for (int dt = 0; dt < 4; ++dt)
            #pragma unroll
            for (int r = 0; r < 4; ++r) pmax = fmaxf(pmax, sc[dt][r]);
        pmax = fmaxf(pmax, __shfl_xor(pmax, 16, 64));
        pmax = fmaxf(pmax, __shfl_xor(pmax, 32, 64));
        pmax += c;                                    // effective max incl. bias
        if (__any(pmax > m + 8.f)) {
            float mn = fmaxf(m, pmax);
            float scale = __expf(m - mn);
            l *= scale;
            #pragma unroll
            for (int odt = 0; odt < 4; ++odt)
                #pragma unroll
                for (int r = 0; r < 4; ++r) acc_o[odt][r] *= scale;
            m = mn;
        }
        float moff = m - c;                           // P = exp(sc + c - m)
        float rs = 0.f;
        #pragma unroll
        for (int dt = 0; dt < 4; ++dt)
            #pragma unroll
            for (int r = 0; r < 4; ++r) {
                float p = __expf(sc[dt][r] - moff);
                sc[dt][r] = p;
                rs += p;
            }
        rs += __shfl_xor(rs, 16, 64);
        rs += __shfl_xor(rs, 32, 64);
        l += rs;

        // pack P to fp16 B-fragments for 16x16x16 MFMA (k=4*lg+e matches)
        half4 pf[4];
        #pragma unroll
        for (int dt = 0; dt < 4; ++dt)
            pf[dt] = { (_Float16)sc[dt][0], (_Float16)sc[dt][1],
                       (_Float16)sc[dt][2], (_Float16)sc[dt][3] };

        // PV: acc_o[odt] (= O^T[d=odt*16+4lg+r][q=lr]) += V^T frag x P frag
        __builtin_amdgcn_s_setprio(1);
        #pragma unroll
        for (int odt = 0; odt < 4; ++odt)
            #pragma unroll
            for (int dt = 0; dt < 4; ++dt) {
                half4 vf = *(const half4*)(&vs[(odt * 16 + lr) * 72 + dt * 16 + 4 * lg]);
                acc_o[odt] = mfma16(vf, pf[dt], acc_o[odt]);
            }
        __builtin_amdgcn_s_setprio(0);

        if (key0 + 64 < SS) {
            ATTN_WRITE(cur ^ 1, key0 + 64);   // waits vmcnt for regs, fills other buf
            __syncthreads();                  // single barrier per tile
            cur ^= 1;
        }
    }

    // epilogue: lane writes its q-row, d = odt*16 + 4*lg + r (half4 stores)
    float inv = 1.f / l;
    _Float16* orow = O + (size_t)(b * SS + q0 + w * 16 + lr) * 1024 + h * 64;
    #pragma unroll
    for (int odt = 0; odt < 4; ++odt) {
        half4 o = { (_Float16)(acc_o[odt][0] * inv), (_Float16)(acc_o[odt][1] * inv),
                    (_Float16)(acc_o[odt][2] * inv), (_Float16)(acc_o[odt][3] * inv) };
        *(half4*)(orow + odt * 16 + 4 * lg) = o;
    }
#undef ATTN_LOAD
#undef ATTN_WRITE
}

// ---------------------------------------------------------------------------
extern "C" void kernel_launch(void* const* d_in, const int* in_sizes, int n_in,
                              void* d_out, int out_size, void* d_ws, size_t ws_size,
                              hipStream_t stream)
{
    const float* x   = (const float*)d_in[0];
    const float* Wq  = (const float*)d_in[1];
    const float* Wk  = (const float*)d_in[2];
    const float* Wv  = (const float*)d_in[3];
    const float* Wo  = (const float*)d_in[4];
    const float* ksc = (const float*)d_in[5];
    // d_in[6] (value_scale) intentionally unused — reference pools raw Wv
    const float* bias_emb = (const float*)d_in[7];
    float* out = (float*)d_out;

    char* ws = (char*)d_ws;
    // workspace layout (bytes); Wqk and Wvb MUST be adjacent (fused GEMM B)
    _Float16* Wqk = (_Float16*)(ws);                  // 1280*1024*2 =  2,621,440
    _Float16* Wvb = (_Float16*)(ws + 2621440);        //  256*1024*2 =    524,288
    _Float16* Wob = (_Float16*)(ws + 3145728);        // 1024*1024*2 =  2,097,152
    float*    tab = (float*)(ws + 5242880);           // 16*4095*4   =    262,080 (+pad)
    _Float16* Xh  = (_Float16*)(ws + 5505024);        // 4096*1024*2 =  8,388,608
    _Float16* Y   = (_Float16*)(ws + 13893632);       // 4096*1280*2 = 10,485,760
    _Float16* Vt  = (_Float16*)(ws + 24379392);       //  256*4096*2 =  2,097,152
    _Float16* Ob  = (_Float16*)(ws + 26476544);       // 4096*1024*2 =  8,388,608
    // total: 34,865,152 bytes

    prep_weights<<<2560, 256, 0, stream>>>(Wq, Wk, Wv, Wo, ksc, Wqk, Wvb, Wob);
    cast_x<<<4096, 256, 0, stream>>>(x, Xh);
    build_bias<<<256, 256, 0, stream>>>(bias_emb, tab);

    // fused Q|K|V projection: [4096,1024] @ [1536,1024]^T
    // cols 0..1279 -> Y row-major; cols 1280..1535 -> Vt transposed
    gemm_bt<3><<<dim3(12, 32), 256, 0, stream>>>(Xh, Wqk, Y, Vt, 4096, 1024, NQK);

    // flash attention: 32 q-tiles x 16 heads x 2 batches
    attn<<<1024, 256, 0, stream>>>(Y, Vt, tab, Ob);

    // output projection: [4096,1024] @ [1024,1024]^T -> fp32 out
    gemm_bt<0><<<dim3(8, 32), 256, 0, stream>>>(Ob, Wob, out, nullptr, 4096, 1024, 1024);
}

// Round 7
// 133.454 us; speedup vs baseline: 2.3851x; 1.0864x over previous
//
#include <hip/hip_runtime.h>

using half8  = __attribute__((ext_vector_type(8))) _Float16;
using half4  = __attribute__((ext_vector_type(4))) _Float16;
using half2v = __attribute__((ext_vector_type(2))) _Float16;
using fp16x2 = __attribute__((ext_vector_type(2))) __fp16;
using f32x4  = __attribute__((ext_vector_type(4))) float;

#define BB 2
#define SS 2048
#define DD 1024
#define HH 16
#define KVH 4
#define HDIM 64
#define NQK 1280    // Q(1024) | K(256) columns of QK projection
#define LOG2E 1.4426950408889634f

// async global->LDS, 16B per lane, linear LDS dest (wave-uniform base + lane*16)
#define GLDS(g, l) __builtin_amdgcn_global_load_lds( \
    (const __attribute__((address_space(1))) void*)(g), \
    (__attribute__((address_space(3))) void*)(l), 16, 0, 0)

__device__ __forceinline__ f32x4 mfma16(half4 a, half4 b, f32x4 c) {
    return __builtin_amdgcn_mfma_f32_16x16x16f16(a, b, c, 0, 0, 0);
}

__device__ __forceinline__ float fexp2(float x) {
#if __has_builtin(__builtin_amdgcn_exp2f)
    return __builtin_amdgcn_exp2f(x);
#else
    return exp2f(x);
#endif
}

__device__ __forceinline__ half2v cvt_pk_f16(float a, float b) {
    fp16x2 r = __builtin_amdgcn_cvt_pkrtz(a, b);
    return __builtin_bit_cast(half2v, r);
}

// T5 bucket via integer thresholds (matches numpy fp32 logf semantics at all
// integer rel positions; verified boundary cases 12/16/23/32/46/64/91).
__device__ __forceinline__ int rel_large(int rel) { // rel >= 8
    int n;
    if (rel < 12) n = 0; else if (rel < 16) n = 1; else if (rel < 23) n = 2;
    else if (rel < 32) n = 3; else if (rel < 46) n = 4; else if (rel < 64) n = 5;
    else if (rel < 91) n = 6; else if (rel < 128) n = 7; else n = 8;
    int large = 8 + n;
    return large > 15 ? 15 : large;
}

// ---------------------------------------------------------------------------
// Fused prep: blocks 0..2559 -> weights; 2560..6655 -> cast x; 6656..6911 ->
// bias table. Q-rows of Wqk and the bias table are PRE-SCALED by log2e so the
// attention softmax runs in exp2 domain (saves a v_mul per exp).
// rows 1280..1535 use RAW pooled Wv (value_scale unused: reference bug).
__global__ void prep_all(const float* __restrict__ x,
                         const float* __restrict__ Wq, const float* __restrict__ Wk,
                         const float* __restrict__ Wv, const float* __restrict__ Wo,
                         const float* __restrict__ ksc, const float* __restrict__ bias_emb,
                         _Float16* __restrict__ Wqk, _Float16* __restrict__ Wvb,
                         _Float16* __restrict__ Wob, float* __restrict__ tab,
                         _Float16* __restrict__ Xh)
{
    int bid = blockIdx.x;
    if (bid < 2560) {
        int row = bid;
        int c = threadIdx.x * 4;
        if (row < NQK) {
            if (row < 1024) {
                #pragma unroll
                for (int j = 0; j < 4; ++j)
                    Wqk[(size_t)row * DD + c + j] = (_Float16)(Wq[(size_t)row * DD + c + j] * LOG2E);
            } else {
                int kh = row - 1024;                  // 0..255
                int kvi = kh >> 6, hd = kh & 63;
                #pragma unroll
                for (int j = 0; j < 4; ++j) {
                    float s = 0.f;
                    #pragma unroll
                    for (int g = 0; g < 4; ++g)
                        s += Wk[(size_t)((kvi * 4 + g) * 64 + hd) * DD + c + j] * ksc[kvi * 4 + g];
                    Wqk[(size_t)row * DD + c + j] = (_Float16)s;
                }
            }
        } else if (row < 1536) {
            int vh = row - 1280;
            int kvi = vh >> 6, hd = vh & 63;
            #pragma unroll
            for (int j = 0; j < 4; ++j) {
                float s = 0.f;
                #pragma unroll
                for (int g = 0; g < 4; ++g)
                    s += Wv[(size_t)((kvi * 4 + g) * 64 + hd) * DD + c + j];
                Wvb[(size_t)vh * DD + c + j] = (_Float16)s;
            }
        } else {
            int r = row - 1536;
            #pragma unroll
            for (int j = 0; j < 4; ++j)
                Wob[(size_t)r * DD + c + j] = (_Float16)Wo[(size_t)r * DD + c + j];
        }
    } else if (bid < 6656) {
        int idx = ((bid - 2560) * 256 + threadIdx.x) * 4;
        float4 v = *(const float4*)(x + idx);
        half4 o = { (_Float16)v.x, (_Float16)v.y, (_Float16)v.z, (_Float16)v.w };
        *(half4*)(Xh + idx) = o;
    } else {
        int idx = (bid - 6656) * 256 + threadIdx.x;
        if (idx < HH * 4095) {
            int h = idx / 4095;
            int dpos = idx % 4095;
            int d = dpos - 2047;
            int rel = d < 0 ? -d : d;
            int bucket = (rel < 8) ? rel : rel_large(rel);
            if (d > 0) bucket += 16;
            tab[(size_t)h * 4095 + dpos] = bias_emb[bucket * HH + h] * LOG2E;
        }
    }
}

// ---------------------------------------------------------------------------
// C = A[M,K] @ B[N,K]^T, fp16 in, fp32 accum. 128x128 tile, BK=32, 4 waves,
// 2-PHASE double-buffered global_load_lds: issue next tile's loads BEFORE
// compute, one barrier per K-step (load latency hides under MFMA+ds_read).
// Bijective XCD swizzle on the linearized block id (grid size % 8 == 0).
// OUTK 0: C0 fp32 row-major (ldc stride).
// OUTK 3: fused projection output: cols < 1280 -> C0 fp16 row-major (ldc);
//         cols >= 1280 -> C1 fp16 TRANSPOSED (C1[(col-1280)*M + row]).
template<int OUTK>
__global__ __launch_bounds__(256) void gemm_bt(const _Float16* __restrict__ A,
                                               const _Float16* __restrict__ B,
                                               void* __restrict__ C0,
                                               _Float16* __restrict__ C1,
                                               int M, int K, int ldc)
{
    __shared__ __align__(16) _Float16 As[2][128 * 32];
    __shared__ __align__(16) _Float16 Bs[2][128 * 32];

    // XCD-bijective remap of linear block id
    int nwg = gridDim.x * gridDim.y;
    int lid = blockIdx.y * gridDim.x + blockIdx.x;
    int sid = (lid & 7) * (nwg >> 3) + (lid >> 3);
    int m0 = (sid / gridDim.x) * 128, n0 = (sid % gridDim.x) * 128;

    int t = threadIdx.x;
    int wv = t >> 6, lane = t & 63;
    int wm = wv >> 1, wn = wv & 1;
    int lr = lane & 15, lg = lane >> 4;
    int srow = lane >> 2;            // 0..15 within chunk
    int scol = (lane & 3) << 3;      // 0,8,16,24 halves
    f32x4 acc[4][4] = {};

#define GSTAGE(BUF, K0)                                                       \
    {                                                                         \
        _Pragma("unroll")                                                     \
        for (int i_ = 0; i_ < 2; ++i_) {                                      \
            int chunk_ = wv * 2 + i_;                                         \
            int row_ = chunk_ * 16 + srow;                                    \
            GLDS(A + (size_t)(m0 + row_) * K + (K0) + scol,                   \
                 &As[BUF][chunk_ * 512 + lane * 8]);                          \
            GLDS(B + (size_t)(n0 + row_) * K + (K0) + scol,                   \
                 &Bs[BUF][chunk_ * 512 + lane * 8]);                          \
        }                                                                     \
    }

    GSTAGE(0, 0);
    __syncthreads();          // drains vmcnt -> buf0 ready
    int cur = 0;

    for (int k0 = 0; k0 < K; k0 += 32) {
        if (k0 + 32 < K) GSTAGE(cur ^ 1, k0 + 32);   // async prefetch
        half8 af[4], bfr[4];
        #pragma unroll
        for (int mi = 0; mi < 4; ++mi)
            af[mi] = *(const half8*)(&As[cur][(wm * 64 + mi * 16 + lr) * 32 + lg * 8]);
        #pragma unroll
        for (int ni = 0; ni < 4; ++ni)
            bfr[ni] = *(const half8*)(&Bs[cur][(wn * 64 + ni * 16 + lr) * 32 + lg * 8]);
        __builtin_amdgcn_s_setprio(1);
        #pragma unroll
        for (int mi = 0; mi < 4; ++mi)
            #pragma unroll
            for (int ni = 0; ni < 4; ++ni)
                acc[mi][ni] = __builtin_amdgcn_mfma_f32_16x16x32_f16(af[mi], bfr[ni], acc[mi][ni], 0, 0, 0);
        __builtin_amdgcn_s_setprio(0);
        __syncthreads();      // drains prefetch vmcnt; readers of cur done
        cur ^= 1;
    }
#undef GSTAGE

    #pragma unroll
    for (int mi = 0; mi < 4; ++mi) {
        #pragma unroll
        for (int ni = 0; ni < 4; ++ni) {
            int rowb = m0 + wm * 64 + mi * 16 + 4 * lg;
            int col  = n0 + wn * 64 + ni * 16 + lr;
            if constexpr (OUTK == 0) {
                #pragma unroll
                for (int r = 0; r < 4; ++r)
                    ((float*)C0)[(size_t)(rowb + r) * ldc + col] = acc[mi][ni][r];
            } else {
                if (n0 < 1280) {
                    #pragma unroll
                    for (int r = 0; r < 4; ++r)
                        ((_Float16*)C0)[(size_t)(rowb + r) * ldc + col] = (_Float16)acc[mi][ni][r];
                } else {
                    half4 o = { (_Float16)acc[mi][ni][0], (_Float16)acc[mi][ni][1],
                                (_Float16)acc[mi][ni][2], (_Float16)acc[mi][ni][3] };
                    *(half4*)(C1 + (size_t)(col - 1280) * M + rowb) = o;
                }
            }
        }
    }
}

// ---------------------------------------------------------------------------
// Flash attention, swapped-operand QK^T, fp16, double-buffered async staging,
// exp2-domain softmax (Q and bias pre-scaled by log2e at prep).
// One block = 64 q-rows of one (b,h); lane's q-row = lr (partners ^16, ^32).
// Far tiles (|key0-q0| >= 192): rel-pos bucket saturated -> uniform bias,
// folded into the softmax offset (no per-element bias loads/adds).
__global__ __launch_bounds__(256) void attn(const _Float16* __restrict__ Y,
                                            const _Float16* __restrict__ Vt,
                                            const float* __restrict__ tab,
                                            _Float16* __restrict__ O)
{
    // bijective XCD swizzle: blocks sharing a (b,kv) K/V slab (128 consecutive
    // logical ids) land on one XCD's L2. 1024 = 8 * 128 exactly.
    int blk = (blockIdx.x & 7) * 128 + (blockIdx.x >> 3);
    int qb = blk & 31, h = (blk >> 5) & 15, b = blk >> 9;
    int kv = h >> 2;
    int q0 = qb * 64;
    int t = threadIdx.x, w = t >> 6, lane = t & 63, lr = lane & 15, lg = lane >> 4;

    __shared__ __align__(16) _Float16 Ks[2][64 * 72];
    __shared__ __align__(16) _Float16 Vst[2][64 * 72];
    __shared__ float bias_s[2][128];

    const size_t yoff = (size_t)(b * SS + q0 + w * 16 + lr) * NQK + h * 64;
    half8 aq0 = *(const half8*)(Y + yoff + lg * 8);
    half8 aq1 = *(const half8*)(Y + yoff + 32 + lg * 8);

    // far-tile uniform bias values (bucket saturated at |d|>=128), log2-scaled
    const float bias_neg = tab[(size_t)h * 4095 + 0];      // key << q
    const float bias_pos = tab[(size_t)h * 4095 + 4094];   // key >> q

    f32x4 acc_o[4] = {};
    float m = -1e30f, l = 0.f;
    const int bb = 63 - w * 16 - lr + 4 * lg;   // bias base: + dt*16 + r

    // staging registers
    uint4 kreg0, kreg1, vreg0, vreg1;
    float breg = 0.f;
    const int srow = t >> 3, sc8 = (t & 7) << 3;        // chunk 0: rows 0..31
    const int srow1 = srow + 32;                        // chunk 1: rows 32..63

#define ATTN_LOAD(KEY0)                                                          \
    {                                                                            \
        int k0_ = (KEY0);                                                        \
        kreg0 = *(const uint4*)(Y + (size_t)(b * SS + k0_ + srow)  * NQK + 1024 + kv * 64 + sc8); \
        kreg1 = *(const uint4*)(Y + (size_t)(b * SS + k0_ + srow1) * NQK + 1024 + kv * 64 + sc8); \
        vreg0 = *(const uint4*)(Vt + (size_t)(kv * 64 + srow)  * 4096 + b * SS + k0_ + sc8); \
        vreg1 = *(const uint4*)(Vt + (size_t)(kv * 64 + srow1) * 4096 + b * SS + k0_ + sc8); \
        bool far_ = (k0_ >= q0 + 192) || (k0_ <= q0 - 192);                      \
        if (!far_ && t < 128) {                                                  \
            int ti = k0_ - q0 + t - 63 + 2047;                                   \
            ti = ti < 0 ? 0 : (ti > 4094 ? 4094 : ti);                           \
            breg = tab[(size_t)h * 4095 + ti];                                   \
        }                                                                        \
    }

#define ATTN_WRITE(BUF, KEY0)                                                    \
    {                                                                            \
        int bf_ = (BUF);                                                         \
        *(uint4*)(&Ks[bf_][srow  * 72 + sc8]) = kreg0;                           \
        *(uint4*)(&Ks[bf_][srow1 * 72 + sc8]) = kreg1;                           \
        *(uint4*)(&Vst[bf_][srow  * 72 + sc8]) = vreg0;                          \
        *(uint4*)(&Vst[bf_][srow1 * 72 + sc8]) = vreg1;                          \
        bool far_ = ((KEY0) >= q0 + 192) || ((KEY0) <= q0 - 192);                \
        if (!far_ && t < 128) bias_s[bf_][t] = breg;                             \
    }

    ATTN_LOAD(0);
    ATTN_WRITE(0, 0);
    __syncthreads();
    int cur = 0;

    for (int key0 = 0; key0 < SS; key0 += 64) {
        if (key0 + 64 < SS) ATTN_LOAD(key0 + 64);   // async: regs used only in WRITE

        const _Float16* ks = Ks[cur];
        const _Float16* vs = Vst[cur];
        bool far = (key0 >= q0 + 192) || (key0 <= q0 - 192);

        // swapped QK^T: sc[dt][r] = S2[key=key0+dt*16+4lg+r][q=lr] (log2 units)
        f32x4 z = {0.f, 0.f, 0.f, 0.f};
        f32x4 sc[4];
        __builtin_amdgcn_s_setprio(1);
        #pragma unroll
        for (int dt = 0; dt < 4; ++dt) {
            half8 bk0 = *(const half8*)(&ks[(dt * 16 + lr) * 72 + lg * 8]);
            half8 bk1 = *(const half8*)(&ks[(dt * 16 + lr) * 72 + 32 + lg * 8]);
            sc[dt] = __builtin_amdgcn_mfma_f32_16x16x32_f16(bk0, aq0, z, 0, 0, 0);
            sc[dt] = __builtin_amdgcn_mfma_f32_16x16x32_f16(bk1, aq1, sc[dt], 0, 0, 0);
        }
        __builtin_amdgcn_s_setprio(0);

        float c;
        if (!far) {
            #pragma unroll
            for (int dt = 0; dt < 4; ++dt)
                #pragma unroll
                for (int r = 0; r < 4; ++r)
                    sc[dt][r] += bias_s[cur][bb + dt * 16 + r];
            c = 0.f;
        } else {
            c = (key0 > q0) ? bias_pos : bias_neg;
        }

        // per-lane online softmax with deferred rescale (THR=8 log2-units)
        float pmax = sc[0][0];
        #pragma unroll
        for (int dt = 0; dt < 4; ++dt)
            #pragma unroll
            for (int r = 0; r < 4; ++r) pmax = fmaxf(pmax, sc[dt][r]);
        pmax = fmaxf(pmax, __shfl_xor(pmax, 16, 64));
        pmax = fmaxf(pmax, __shfl_xor(pmax, 32, 64));
        pmax += c;                                    // effective max incl. bias
        if (__any(pmax > m + 8.f)) {
            float mn = fmaxf(m, pmax);
            float scale = fexp2(m - mn);
            l *= scale;
            #pragma unroll
            for (int odt = 0; odt < 4; ++odt)
                #pragma unroll
                for (int r = 0; r < 4; ++r) acc_o[odt][r] *= scale;
            m = mn;
        }
        float moff = m - c;                           // P = 2^(sc + c - m)
        float rs = 0.f;
        #pragma unroll
        for (int dt = 0; dt < 4; ++dt)
            #pragma unroll
            for (int r = 0; r < 4; ++r) {
                float p = fexp2(sc[dt][r] - moff);
                sc[dt][r] = p;
                rs += p;
            }
        rs += __shfl_xor(rs, 16, 64);
        rs += __shfl_xor(rs, 32, 64);
        l += rs;

        // pack P to fp16 B-fragments (k=4*lg+e matches 16x16x16 B layout)
        half4 pf[4];
        #pragma unroll
        for (int dt = 0; dt < 4; ++dt) {
            half2v p01 = cvt_pk_f16(sc[dt][0], sc[dt][1]);
            half2v p23 = cvt_pk_f16(sc[dt][2], sc[dt][3]);
            pf[dt] = { p01[0], p01[1], p23[0], p23[1] };
        }

        // PV: acc_o[odt] (= O^T[d=odt*16+4lg+r][q=lr]) += V^T frag x P frag
        __builtin_amdgcn_s_setprio(1);
        #pragma unroll
        for (int odt = 0; odt < 4; ++odt)
            #pragma unroll
            for (int dt = 0; dt < 4; ++dt) {
                half4 vf = *(const half4*)(&vs[(odt * 16 + lr) * 72 + dt * 16 + 4 * lg]);
                acc_o[odt] = mfma16(vf, pf[dt], acc_o[odt]);
            }
        __builtin_amdgcn_s_setprio(0);

        if (key0 + 64 < SS) {
            ATTN_WRITE(cur ^ 1, key0 + 64);   // waits vmcnt for regs, fills other buf
            __syncthreads();                  // single barrier per tile
            cur ^= 1;
        }
    }

    // epilogue: lane writes its q-row, d = odt*16 + 4*lg + r (half4 stores)
    float inv = 1.f / l;
    _Float16* orow = O + (size_t)(b * SS + q0 + w * 16 + lr) * 1024 + h * 64;
    #pragma unroll
    for (int odt = 0; odt < 4; ++odt) {
        half4 o = { (_Float16)(acc_o[odt][0] * inv), (_Float16)(acc_o[odt][1] * inv),
                    (_Float16)(acc_o[odt][2] * inv), (_Float16)(acc_o[odt][3] * inv) };
        *(half4*)(orow + odt * 16 + 4 * lg) = o;
    }
#undef ATTN_LOAD
#undef ATTN_WRITE
}

// ---------------------------------------------------------------------------
extern "C" void kernel_launch(void* const* d_in, const int* in_sizes, int n_in,
                              void* d_out, int out_size, void* d_ws, size_t ws_size,
                              hipStream_t stream)
{
    const float* x   = (const float*)d_in[0];
    const float* Wq  = (const float*)d_in[1];
    const float* Wk  = (const float*)d_in[2];
    const float* Wv  = (const float*)d_in[3];
    const float* Wo  = (const float*)d_in[4];
    const float* ksc = (const float*)d_in[5];
    // d_in[6] (value_scale) intentionally unused — reference pools raw Wv
    const float* bias_emb = (const float*)d_in[7];
    float* out = (float*)d_out;

    char* ws = (char*)d_ws;
    // workspace layout (bytes); Wqk and Wvb MUST be adjacent (fused GEMM B)
    _Float16* Wqk = (_Float16*)(ws);                  // 1280*1024*2 =  2,621,440
    _Float16* Wvb = (_Float16*)(ws + 2621440);        //  256*1024*2 =    524,288
    _Float16* Wob = (_Float16*)(ws + 3145728);        // 1024*1024*2 =  2,097,152
    float*    tab = (float*)(ws + 5242880);           // 16*4095*4   =    262,080 (+pad)
    _Float16* Xh  = (_Float16*)(ws + 5505024);        // 4096*1024*2 =  8,388,608
    _Float16* Y   = (_Float16*)(ws + 13893632);       // 4096*1280*2 = 10,485,760
    _Float16* Vt  = (_Float16*)(ws + 24379392);       //  256*4096*2 =  2,097,152
    _Float16* Ob  = (_Float16*)(ws + 26476544);       // 4096*1024*2 =  8,388,608
    // total: 34,865,152 bytes

    // fused prep: weights (log2e-folded Q), x cast, bias table (log2e-scaled)
    prep_all<<<6912, 256, 0, stream>>>(x, Wq, Wk, Wv, Wo, ksc, bias_emb,
                                       Wqk, Wvb, Wob, tab, Xh);

    // fused Q|K|V projection: [4096,1024] @ [1536,1024]^T
    // cols 0..1279 -> Y row-major; cols 1280..1535 -> Vt transposed
    gemm_bt<3><<<dim3(12, 32), 256, 0, stream>>>(Xh, Wqk, Y, Vt, 4096, 1024, NQK);

    // flash attention: 32 q-tiles x 16 heads x 2 batches
    attn<<<1024, 256, 0, stream>>>(Y, Vt, tab, Ob);

    // output projection: [4096,1024] @ [1024,1024]^T -> fp32 out
    gemm_bt<0><<<dim3(8, 32), 256, 0, stream>>>(Ob, Wob, out, nullptr, 4096, 1024, 1024);
}

// Round 8
// 131.599 us; speedup vs baseline: 2.4187x; 1.0141x over previous
//
#include <hip/hip_runtime.h>

using half8  = __attribute__((ext_vector_type(8))) _Float16;
using half4  = __attribute__((ext_vector_type(4))) _Float16;
using half2v = __attribute__((ext_vector_type(2))) _Float16;
using fp16x2 = __attribute__((ext_vector_type(2))) __fp16;
using f32x4  = __attribute__((ext_vector_type(4))) float;

#define BB 2
#define SS 2048
#define DD 1024
#define HH 16
#define KVH 4
#define HDIM 64
#define NQK 1280    // Q(1024) | K(256) columns of QK projection
#define LOG2E 1.4426950408889634f

// async global->LDS, 16B per lane, linear LDS dest (wave-uniform base + lane*16)
#define GLDS(g, l) __builtin_amdgcn_global_load_lds( \
    (const __attribute__((address_space(1))) void*)(g), \
    (__attribute__((address_space(3))) void*)(l), 16, 0, 0)

__device__ __forceinline__ f32x4 mfma16(half4 a, half4 b, f32x4 c) {
    return __builtin_amdgcn_mfma_f32_16x16x16f16(a, b, c, 0, 0, 0);
}

__device__ __forceinline__ float fexp2(float x) {
#if __has_builtin(__builtin_amdgcn_exp2f)
    return __builtin_amdgcn_exp2f(x);
#else
    return exp2f(x);
#endif
}

__device__ __forceinline__ half2v cvt_pk_f16(float a, float b) {
    fp16x2 r = __builtin_amdgcn_cvt_pkrtz(a, b);
    return __builtin_bit_cast(half2v, r);
}

// Attn K/V LDS tile [64 rows][64 halves], row stride 128B, XOR-swizzled 16B
// slots: slot' = slot ^ (row & 7). Returns offset in halves. Applied on BOTH
// ds_write (staging) and all ds_reads (rule: both-sides-or-neither).
__device__ __forceinline__ int kv_off(int row, int hcol) {
    return row * 64 + ((((hcol >> 3) ^ row) & 7) << 3) + (hcol & 7);
}

// GEMM LDS tile [128 rows][32 halves], row stride 64B, XOR-swizzled 16B slots:
// slot' = slot ^ (row & 3). Reader-side helper (writer swizzles GLDS source).
__device__ __forceinline__ int gm_off(int row, int slot) {
    return row * 32 + (((slot ^ row) & 3) << 3);
}

// T5 bucket via integer thresholds (matches numpy fp32 logf semantics at all
// integer rel positions; verified boundary cases 12/16/23/32/46/64/91).
__device__ __forceinline__ int rel_large(int rel) { // rel >= 8
    int n;
    if (rel < 12) n = 0; else if (rel < 16) n = 1; else if (rel < 23) n = 2;
    else if (rel < 32) n = 3; else if (rel < 46) n = 4; else if (rel < 64) n = 5;
    else if (rel < 91) n = 6; else if (rel < 128) n = 7; else n = 8;
    int large = 8 + n;
    return large > 15 ? 15 : large;
}

// ---------------------------------------------------------------------------
// Fused prep: blocks 0..2559 -> weights; 2560..6655 -> cast x; 6656..6911 ->
// bias table. Q-rows of Wqk and the bias table are PRE-SCALED by log2e so the
// attention softmax runs in exp2 domain.
// rows 1280..1535 use RAW pooled Wv (value_scale unused: reference bug).
__global__ void prep_all(const float* __restrict__ x,
                         const float* __restrict__ Wq, const float* __restrict__ Wk,
                         const float* __restrict__ Wv, const float* __restrict__ Wo,
                         const float* __restrict__ ksc, const float* __restrict__ bias_emb,
                         _Float16* __restrict__ Wqk, _Float16* __restrict__ Wvb,
                         _Float16* __restrict__ Wob, float* __restrict__ tab,
                         _Float16* __restrict__ Xh)
{
    int bid = blockIdx.x;
    if (bid < 2560) {
        int row = bid;
        int c = threadIdx.x * 4;
        if (row < NQK) {
            if (row < 1024) {
                #pragma unroll
                for (int j = 0; j < 4; ++j)
                    Wqk[(size_t)row * DD + c + j] = (_Float16)(Wq[(size_t)row * DD + c + j] * LOG2E);
            } else {
                int kh = row - 1024;                  // 0..255
                int kvi = kh >> 6, hd = kh & 63;
                #pragma unroll
                for (int j = 0; j < 4; ++j) {
                    float s = 0.f;
                    #pragma unroll
                    for (int g = 0; g < 4; ++g)
                        s += Wk[(size_t)((kvi * 4 + g) * 64 + hd) * DD + c + j] * ksc[kvi * 4 + g];
                    Wqk[(size_t)row * DD + c + j] = (_Float16)s;
                }
            }
        } else if (row < 1536) {
            int vh = row - 1280;
            int kvi = vh >> 6, hd = vh & 63;
            #pragma unroll
            for (int j = 0; j < 4; ++j) {
                float s = 0.f;
                #pragma unroll
                for (int g = 0; g < 4; ++g)
                    s += Wv[(size_t)((kvi * 4 + g) * 64 + hd) * DD + c + j];
                Wvb[(size_t)vh * DD + c + j] = (_Float16)s;
            }
        } else {
            int r = row - 1536;
            #pragma unroll
            for (int j = 0; j < 4; ++j)
                Wob[(size_t)r * DD + c + j] = (_Float16)Wo[(size_t)r * DD + c + j];
        }
    } else if (bid < 6656) {
        int idx = ((bid - 2560) * 256 + threadIdx.x) * 4;
        float4 v = *(const float4*)(x + idx);
        half4 o = { (_Float16)v.x, (_Float16)v.y, (_Float16)v.z, (_Float16)v.w };
        *(half4*)(Xh + idx) = o;
    } else {
        int idx = (bid - 6656) * 256 + threadIdx.x;
        if (idx < HH * 4095) {
            int h = idx / 4095;
            int dpos = idx % 4095;
            int d = dpos - 2047;
            int rel = d < 0 ? -d : d;
            int bucket = (rel < 8) ? rel : rel_large(rel);
            if (d > 0) bucket += 16;
            tab[(size_t)h * 4095 + dpos] = bias_emb[bucket * HH + h] * LOG2E;
        }
    }
}

// ---------------------------------------------------------------------------
// C = A[M,K] @ B[N,K]^T, fp16 in, fp32 accum. 128x128 tile, BK=32, 4 waves,
// 2-PHASE double-buffered global_load_lds, XOR-swizzled LDS (pre-swizzled
// global source column -> linear GLDS dest holds swizzled layout; reads XOR).
// OUTK 0: C0 fp32 row-major (ldc stride).
// OUTK 3: fused projection output: cols < 1280 -> C0 fp16 row-major (ldc);
//         cols >= 1280 -> C1 fp16 TRANSPOSED (C1[(col-1280)*M + row]).
template<int OUTK>
__global__ __launch_bounds__(256) void gemm_bt(const _Float16* __restrict__ A,
                                               const _Float16* __restrict__ B,
                                               void* __restrict__ C0,
                                               _Float16* __restrict__ C1,
                                               int M, int K, int ldc)
{
    __shared__ __align__(16) _Float16 As[2][128 * 32];
    __shared__ __align__(16) _Float16 Bs[2][128 * 32];

    // XCD-bijective remap of linear block id
    int nwg = gridDim.x * gridDim.y;
    int lid = blockIdx.y * gridDim.x + blockIdx.x;
    int sid = (lid & 7) * (nwg >> 3) + (lid >> 3);
    int m0 = (sid / gridDim.x) * 128, n0 = (sid % gridDim.x) * 128;

    int t = threadIdx.x;
    int wv = t >> 6, lane = t & 63;
    int wm = wv >> 1, wn = wv & 1;
    int lr = lane & 15, lg = lane >> 4;
    int srow = lane >> 2;            // 0..15 within chunk (row = chunk*16+srow)
    // pre-swizzled source column: lane's LDS slot is (lane&3); it must hold
    // logical slot (lane&3)^(row&3), row&3 = (lane>>2)&3
    int scol = (((lane & 3) ^ ((lane >> 2) & 3)) << 3);
    f32x4 acc[4][4] = {};

#define GSTAGE(BUF, K0)                                                       \
    {                                                                         \
        _Pragma("unroll")                                                     \
        for (int i_ = 0; i_ < 2; ++i_) {                                      \
            int chunk_ = wv * 2 + i_;                                         \
            int row_ = chunk_ * 16 + srow;                                    \
            GLDS(A + (size_t)(m0 + row_) * K + (K0) + scol,                   \
                 &As[BUF][chunk_ * 512 + lane * 8]);                          \
            GLDS(B + (size_t)(n0 + row_) * K + (K0) + scol,                   \
                 &Bs[BUF][chunk_ * 512 + lane * 8]);                          \
        }                                                                     \
    }

    GSTAGE(0, 0);
    __syncthreads();          // drains vmcnt -> buf0 ready
    int cur = 0;

    for (int k0 = 0; k0 < K; k0 += 32) {
        if (k0 + 32 < K) GSTAGE(cur ^ 1, k0 + 32);   // async prefetch
        half8 af[4], bfr[4];
        #pragma unroll
        for (int mi = 0; mi < 4; ++mi)
            af[mi] = *(const half8*)(&As[cur][gm_off(wm * 64 + mi * 16 + lr, lg)]);
        #pragma unroll
        for (int ni = 0; ni < 4; ++ni)
            bfr[ni] = *(const half8*)(&Bs[cur][gm_off(wn * 64 + ni * 16 + lr, lg)]);
        __builtin_amdgcn_s_setprio(1);
        #pragma unroll
        for (int mi = 0; mi < 4; ++mi)
            #pragma unroll
            for (int ni = 0; ni < 4; ++ni)
                acc[mi][ni] = __builtin_amdgcn_mfma_f32_16x16x32_f16(af[mi], bfr[ni], acc[mi][ni], 0, 0, 0);
        __builtin_amdgcn_s_setprio(0);
        __syncthreads();      // drains prefetch vmcnt; readers of cur done
        cur ^= 1;
    }
#undef GSTAGE

    #pragma unroll
    for (int mi = 0; mi < 4; ++mi) {
        #pragma unroll
        for (int ni = 0; ni < 4; ++ni) {
            int rowb = m0 + wm * 64 + mi * 16 + 4 * lg;
            int col  = n0 + wn * 64 + ni * 16 + lr;
            if constexpr (OUTK == 0) {
                #pragma unroll
                for (int r = 0; r < 4; ++r)
                    ((float*)C0)[(size_t)(rowb + r) * ldc + col] = acc[mi][ni][r];
            } else {
                if (n0 < 1280) {
                    #pragma unroll
                    for (int r = 0; r < 4; ++r)
                        ((_Float16*)C0)[(size_t)(rowb + r) * ldc + col] = (_Float16)acc[mi][ni][r];
                } else {
                    half4 o = { (_Float16)acc[mi][ni][0], (_Float16)acc[mi][ni][1],
                                (_Float16)acc[mi][ni][2], (_Float16)acc[mi][ni][3] };
                    *(half4*)(C1 + (size_t)(col - 1280) * M + rowb) = o;
                }
            }
        }
    }
}

// ---------------------------------------------------------------------------
// Flash attention, swapped-operand QK^T, fp16, double-buffered async staging,
// exp2-domain softmax, XOR-swizzled K/V LDS (conflict-free b128/b64 reads).
// One block = 64 q-rows of one (b,h); lane's q-row = lr (partners ^16, ^32).
// Far tiles (|key0-q0| >= 192): rel-pos bucket saturated -> uniform bias,
// folded into the softmax offset.
__global__ __launch_bounds__(256) void attn(const _Float16* __restrict__ Y,
                                            const _Float16* __restrict__ Vt,
                                            const float* __restrict__ tab,
                                            _Float16* __restrict__ O)
{
    // bijective XCD swizzle: blocks sharing a (b,kv) K/V slab (128 consecutive
    // logical ids) land on one XCD's L2. 1024 = 8 * 128 exactly.
    int blk = (blockIdx.x & 7) * 128 + (blockIdx.x >> 3);
    int qb = blk & 31, h = (blk >> 5) & 15, b = blk >> 9;
    int kv = h >> 2;
    int q0 = qb * 64;
    int t = threadIdx.x, w = t >> 6, lane = t & 63, lr = lane & 15, lg = lane >> 4;

    __shared__ __align__(16) _Float16 Ks[2][64 * 64];
    __shared__ __align__(16) _Float16 Vst[2][64 * 64];
    __shared__ float bias_s[2][128];

    const size_t yoff = (size_t)(b * SS + q0 + w * 16 + lr) * NQK + h * 64;
    half8 aq0 = *(const half8*)(Y + yoff + lg * 8);
    half8 aq1 = *(const half8*)(Y + yoff + 32 + lg * 8);

    // far-tile uniform bias values (bucket saturated at |d|>=128), log2-scaled
    const float bias_neg = tab[(size_t)h * 4095 + 0];      // key << q
    const float bias_pos = tab[(size_t)h * 4095 + 4094];   // key >> q

    f32x4 acc_o[4] = {};
    float m = -1e30f, l = 0.f;
    const int bb = 63 - w * 16 - lr + 4 * lg;   // bias base: + dt*16 + r

    // staging registers
    uint4 kreg0, kreg1, vreg0, vreg1;
    float breg = 0.f;
    const int srow = t >> 3, sc8 = (t & 7) << 3;        // chunk 0: rows 0..31
    const int srow1 = srow + 32;                        // chunk 1: rows 32..63

#define ATTN_LOAD(KEY0)                                                          \
    {                                                                            \
        int k0_ = (KEY0);                                                        \
        kreg0 = *(const uint4*)(Y + (size_t)(b * SS + k0_ + srow)  * NQK + 1024 + kv * 64 + sc8); \
        kreg1 = *(const uint4*)(Y + (size_t)(b * SS + k0_ + srow1) * NQK + 1024 + kv * 64 + sc8); \
        vreg0 = *(const uint4*)(Vt + (size_t)(kv * 64 + srow)  * 4096 + b * SS + k0_ + sc8); \
        vreg1 = *(const uint4*)(Vt + (size_t)(kv * 64 + srow1) * 4096 + b * SS + k0_ + sc8); \
        bool far_ = (k0_ >= q0 + 192) || (k0_ <= q0 - 192);                      \
        if (!far_ && t < 128) {                                                  \
            int ti = k0_ - q0 + t - 63 + 2047;                                   \
            ti = ti < 0 ? 0 : (ti > 4094 ? 4094 : ti);                           \
            breg = tab[(size_t)h * 4095 + ti];                                   \
        }                                                                        \
    }

#define ATTN_WRITE(BUF, KEY0)                                                    \
    {                                                                            \
        int bf_ = (BUF);                                                         \
        *(uint4*)(&Ks[bf_][kv_off(srow,  sc8)]) = kreg0;                         \
        *(uint4*)(&Ks[bf_][kv_off(srow1, sc8)]) = kreg1;                         \
        *(uint4*)(&Vst[bf_][kv_off(srow,  sc8)]) = vreg0;                        \
        *(uint4*)(&Vst[bf_][kv_off(srow1, sc8)]) = vreg1;                        \
        bool far_ = ((KEY0) >= q0 + 192) || ((KEY0) <= q0 - 192);                \
        if (!far_ && t < 128) bias_s[bf_][t] = breg;                             \
    }

    ATTN_LOAD(0);
    ATTN_WRITE(0, 0);
    __syncthreads();
    int cur = 0;

    for (int key0 = 0; key0 < SS; key0 += 64) {
        if (key0 + 64 < SS) ATTN_LOAD(key0 + 64);   // async: regs used only in WRITE

        const _Float16* ks = Ks[cur];
        const _Float16* vs = Vst[cur];
        bool far = (key0 >= q0 + 192) || (key0 <= q0 - 192);

        // swapped QK^T: sc[dt][r] = S2[key=key0+dt*16+4lg+r][q=lr] (log2 units)
        f32x4 z = {0.f, 0.f, 0.f, 0.f};
        f32x4 sc[4];
        __builtin_amdgcn_s_setprio(1);
        #pragma unroll
        for (int dt = 0; dt < 4; ++dt) {
            half8 bk0 = *(const half8*)(&ks[kv_off(dt * 16 + lr, lg * 8)]);
            half8 bk1 = *(const half8*)(&ks[kv_off(dt * 16 + lr, 32 + lg * 8)]);
            sc[dt] = __builtin_amdgcn_mfma_f32_16x16x32_f16(bk0, aq0, z, 0, 0, 0);
            sc[dt] = __builtin_amdgcn_mfma_f32_16x16x32_f16(bk1, aq1, sc[dt], 0, 0, 0);
        }
        __builtin_amdgcn_s_setprio(0);

        float c;
        if (!far) {
            #pragma unroll
            for (int dt = 0; dt < 4; ++dt)
                #pragma unroll
                for (int r = 0; r < 4; ++r)
                    sc[dt][r] += bias_s[cur][bb + dt * 16 + r];
            c = 0.f;
        } else {
            c = (key0 > q0) ? bias_pos : bias_neg;
        }

        // per-lane online softmax with deferred rescale (THR=8 log2-units)
        float pmax = sc[0][0];
        #pragma unroll
        for (int dt = 0; dt < 4; ++dt)
            #pragma unroll
            for (int r = 0; r < 4; ++r) pmax = fmaxf(pmax, sc[dt][r]);
        pmax = fmaxf(pmax, __shfl_xor(pmax, 16, 64));
        pmax = fmaxf(pmax, __shfl_xor(pmax, 32, 64));
        pmax += c;                                    // effective max incl. bias
        if (__any(pmax > m + 8.f)) {
            float mn = fmaxf(m, pmax);
            float scale = fexp2(m - mn);
            l *= scale;
            #pragma unroll
            for (int odt = 0; odt < 4; ++odt)
                #pragma unroll
                for (int r = 0; r < 4; ++r) acc_o[odt][r] *= scale;
            m = mn;
        }
        float moff = m - c;                           // P = 2^(sc + c - m)
        float rs = 0.f;
        #pragma unroll
        for (int dt = 0; dt < 4; ++dt)
            #pragma unroll
            for (int r = 0; r < 4; ++r) {
                float p = fexp2(sc[dt][r] - moff);
                sc[dt][r] = p;
                rs += p;
            }
        rs += __shfl_xor(rs, 16, 64);
        rs += __shfl_xor(rs, 32, 64);
        l += rs;

        // pack P to fp16 B-fragments (k=4*lg+e matches 16x16x16 B layout)
        half4 pf[4];
        #pragma unroll
        for (int dt = 0; dt < 4; ++dt) {
            half2v p01 = cvt_pk_f16(sc[dt][0], sc[dt][1]);
            half2v p23 = cvt_pk_f16(sc[dt][2], sc[dt][3]);
            pf[dt] = { p01[0], p01[1], p23[0], p23[1] };
        }

        // PV: acc_o[odt] (= O^T[d=odt*16+4lg+r][q=lr]) += V^T frag x P frag
        __builtin_amdgcn_s_setprio(1);
        #pragma unroll
        for (int odt = 0; odt < 4; ++odt)
            #pragma unroll
            for (int dt = 0; dt < 4; ++dt) {
                half4 vf = *(const half4*)(&vs[kv_off(odt * 16 + lr, dt * 16 + 4 * lg)]);
                acc_o[odt] = mfma16(vf, pf[dt], acc_o[odt]);
            }
        __builtin_amdgcn_s_setprio(0);

        if (key0 + 64 < SS) {
            ATTN_WRITE(cur ^ 1, key0 + 64);   // waits vmcnt for regs, fills other buf
            __syncthreads();                  // single barrier per tile
            cur ^= 1;
        }
    }

    // epilogue: lane writes its q-row, d = odt*16 + 4*lg + r (half4 stores)
    float inv = 1.f / l;
    _Float16* orow = O + (size_t)(b * SS + q0 + w * 16 + lr) * 1024 + h * 64;
    #pragma unroll
    for (int odt = 0; odt < 4; ++odt) {
        half4 o = { (_Float16)(acc_o[odt][0] * inv), (_Float16)(acc_o[odt][1] * inv),
                    (_Float16)(acc_o[odt][2] * inv), (_Float16)(acc_o[odt][3] * inv) };
        *(half4*)(orow + odt * 16 + 4 * lg) = o;
    }
#undef ATTN_LOAD
#undef ATTN_WRITE
}

// ---------------------------------------------------------------------------
extern "C" void kernel_launch(void* const* d_in, const int* in_sizes, int n_in,
                              void* d_out, int out_size, void* d_ws, size_t ws_size,
                              hipStream_t stream)
{
    const float* x   = (const float*)d_in[0];
    const float* Wq  = (const float*)d_in[1];
    const float* Wk  = (const float*)d_in[2];
    const float* Wv  = (const float*)d_in[3];
    const float* Wo  = (const float*)d_in[4];
    const float* ksc = (const float*)d_in[5];
    // d_in[6] (value_scale) intentionally unused — reference pools raw Wv
    const float* bias_emb = (const float*)d_in[7];
    float* out = (float*)d_out;

    char* ws = (char*)d_ws;
    // workspace layout (bytes); Wqk and Wvb MUST be adjacent (fused GEMM B)
    _Float16* Wqk = (_Float16*)(ws);                  // 1280*1024*2 =  2,621,440
    _Float16* Wvb = (_Float16*)(ws + 2621440);        //  256*1024*2 =    524,288
    _Float16* Wob = (_Float16*)(ws + 3145728);        // 1024*1024*2 =  2,097,152
    float*    tab = (float*)(ws + 5242880);           // 16*4095*4   =    262,080 (+pad)
    _Float16* Xh  = (_Float16*)(ws + 5505024);        // 4096*1024*2 =  8,388,608
    _Float16* Y   = (_Float16*)(ws + 13893632);       // 4096*1280*2 = 10,485,760
    _Float16* Vt  = (_Float16*)(ws + 24379392);       //  256*4096*2 =  2,097,152
    _Float16* Ob  = (_Float16*)(ws + 26476544);       // 4096*1024*2 =  8,388,608
    // total: 34,865,152 bytes

    // fused prep: weights (log2e-folded Q), x cast, bias table (log2e-scaled)
    prep_all<<<6912, 256, 0, stream>>>(x, Wq, Wk, Wv, Wo, ksc, bias_emb,
                                       Wqk, Wvb, Wob, tab, Xh);

    // fused Q|K|V projection: [4096,1024] @ [1536,1024]^T
    // cols 0..1279 -> Y row-major; cols 1280..1535 -> Vt transposed
    gemm_bt<3><<<dim3(12, 32), 256, 0, stream>>>(Xh, Wqk, Y, Vt, 4096, 1024, NQK);

    // flash attention: 32 q-tiles x 16 heads x 2 batches
    attn<<<1024, 256, 0, stream>>>(Y, Vt, tab, Ob);

    // output projection: [4096,1024] @ [1024,1024]^T -> fp32 out
    gemm_bt<0><<<dim3(8, 32), 256, 0, stream>>>(Ob, Wob, out, nullptr, 4096, 1024, 1024);
}